// Round 3
// baseline (515.938 us; speedup 1.0000x reference)
//
#include <hip/hip_runtime.h>
#include <hip/hip_bf16.h>
#include <stdint.h>
#include <stddef.h>
#include <math.h>

typedef __bf16 bf8_t __attribute__((ext_vector_type(8)));
typedef __bf16 bf4_t __attribute__((ext_vector_type(4)));
typedef float  f4_t  __attribute__((ext_vector_type(4)));
typedef unsigned int u32;

#define DEV static __device__ __forceinline__

namespace abc {
constexpr int B = 4, T = 2048, D = 1024, H = 4;
constexpr int BT = B * T;          // 8192
constexpr int CH = 64;             // chunk length
constexpr int NC = T / CH;         // 32 chunks
constexpr int BH = B * H;          // 16
constexpr float SCALE = 0.0625f;   // DK^-0.5
constexpr float GN = 16.0f;
constexpr float EPS = 1e-5f;
}

DEV f4_t mfma16(bf8_t a, bf8_t b, f4_t c) {
  return __builtin_amdgcn_mfma_f32_16x16x32_bf16(a, b, c, 0, 0, 0);
}

// async global->LDS, 16B per lane; lds dest must be wave-uniform base (+lane*16)
DEV void glds16(const void* g, void* l) {
  __builtin_amdgcn_global_load_lds(
      (const __attribute__((address_space(1))) u32*)g,
      (__attribute__((address_space(3))) u32*)l, 16, 0, 0);
}

// ---------------------------------------------------------------------------
// Slice-major pre-swizzled layout for MFMA B-operand matrices (attn path).
// slice = (colchunk cg32 = col/32) x (rowhalf rh = row/128), 4096 elems each:
// group p' = ((row&127)<<2) | (((col>>3)&3) ^ (row&3)).
// ---------------------------------------------------------------------------
DEV __bf16* slice_addr(__bf16* base, int row, int cg /*col/8*/) {
  return base + (((cg >> 2) * 2 + (row >> 7)) * 4096
               + ((((row & 127) << 2) | ((cg & 3) ^ (row & 3))) * 8));
}
DEV const __bf16* slice_addr(const __bf16* base, int row, int cg) {
  return base + (((cg >> 2) * 2 + (row >> 7)) * 4096
               + ((((row & 127) << 2) | ((cg & 3) ^ (row & 3))) * 8));
}

// contiguous slice stage: 8KB, 2 glds16 per wave, fully coalesced (256 thr)
DEV void stage_lin(const __bf16* __restrict__ g, __bf16* lds, int tid) {
  #pragma unroll
  for (int i = 0; i < 2; i++)
    glds16(g + (size_t)(i * 256 + tid) * 8, lds + (i * 256 + (tid & ~63)) * 8);
}

// scattered stage for row-major sources (K, A): ROWSx32col bf16 slice,
// group-XOR-swizzled on the GLOBAL gather side (256 thr).
template<int ROWS>
DEV void stage(const __bf16* __restrict__ g, int S /*elem row stride*/,
               __bf16* lds, int tid) {
  #pragma unroll
  for (int i = 0; i < ROWS / 64; i++) {
    int p = i * 256 + tid;
    int m = p >> 2;
    int q = (p & 3) ^ (m & 3);
    glds16(g + (size_t)m * S + q * 8, lds + (i * 256 + (tid & ~63)) * 8);
  }
}
// read B-fragment (row m, k-group quad) from a staged slice (attn swizzle)
DEV bf8_t bfrag(const __bf16* sl, int m, int quad) {
  return *reinterpret_cast<const bf8_t*>(sl + m * 32 + ((quad ^ (m & 3)) << 3));
}

// counted-vmcnt ring step for attn (2 loads/wave/slice)
DEV void ring_pre(int s) {
  if (s < 46)       asm volatile("s_waitcnt vmcnt(4)" ::: "memory");
  else if (s == 46) asm volatile("s_waitcnt vmcnt(2)" ::: "memory");
  else              asm volatile("s_waitcnt vmcnt(0)" ::: "memory");
  asm volatile("s_waitcnt lgkmcnt(0)" ::: "memory");
  asm volatile("s_barrier" ::: "memory");
}

// ---------------------------------------------------------------------------
// GEMM-local swizzle: XOR uses (row>>1)&3 so the 16-lane ds_read_b128 pattern
// (rows fr*16+l16, fixed quad) spreads across 8 distinct 16B slots (2-way
// conflict = free) instead of 4 (4-way = 1.58x).
// 512-thread staging: 1 glds16/thread per 8KB slice (128 rows x 32 cols).
// ---------------------------------------------------------------------------
DEV void stage_g(const __bf16* __restrict__ g, int S, __bf16* lds, int tid) {
  int m = tid >> 2;
  int q = (tid & 3) ^ ((m >> 1) & 3);
  glds16(g + (size_t)m * S + q * 8, lds + (tid & ~63) * 8);
}
DEV bf8_t bfrag_g(const __bf16* sl, int m, int quad) {
  return *reinterpret_cast<const bf8_t*>(sl + m * 32 + (((quad ^ (m >> 1)) & 3) << 3));
}

// ---------------------------------------------------------------------------
// x fp32 -> bf16 (row-major unchanged). 8 elems/thread.
// ---------------------------------------------------------------------------
__global__ __launch_bounds__(256)
void cvt_x_kernel(const float* __restrict__ x, __bf16* __restrict__ xb)
{
  const int idx = blockIdx.x * 256 + threadIdx.x;   // 1M threads total
  const float4* src = reinterpret_cast<const float4*>(x);
  float4 a = src[(size_t)idx * 2];
  float4 b = src[(size_t)idx * 2 + 1];
  bf8_t o;
  o[0] = (__bf16)a.x; o[1] = (__bf16)a.y; o[2] = (__bf16)a.z; o[3] = (__bf16)a.w;
  o[4] = (__bf16)b.x; o[5] = (__bf16)b.y; o[6] = (__bf16)b.z; o[7] = (__bf16)b.w;
  reinterpret_cast<bf8_t*>(xb)[idx] = o;
}

// ---------------------------------------------------------------------------
// weight fp32 [k][n] -> bf16 [n][k] (transpose), 64x64 tiles, 6 weights
// ---------------------------------------------------------------------------
__global__ __launch_bounds__(256)
void cvt_w_kernel(const float* __restrict__ w0, const float* __restrict__ w1,
                  const float* __restrict__ w2, const float* __restrict__ w3,
                  const float* __restrict__ w4, const float* __restrict__ w5,
                  __bf16* __restrict__ wt)
{
  const int z = blockIdx.z;
  const float* W = (z == 0) ? w0 : (z == 1) ? w1 : (z == 2) ? w2
                 : (z == 3) ? w3 : (z == 4) ? w4 : w5;
  const int n0 = blockIdx.x * 64, k0 = blockIdx.y * 64;
  __shared__ __bf16 Ts[64][72];
  const int tid = threadIdx.x;
  #pragma unroll
  for (int i = 0; i < 4; i++) {
    int p = tid + 256 * i;            // 1024 float4 chunks: 64 k-rows x 16
    int row = p >> 4, c4 = p & 15;
    float4 v = *reinterpret_cast<const float4*>(W + (size_t)(k0 + row) * 1024 + n0 + c4 * 4);
    Ts[c4 * 4 + 0][row] = (__bf16)v.x;
    Ts[c4 * 4 + 1][row] = (__bf16)v.y;
    Ts[c4 * 4 + 2][row] = (__bf16)v.z;
    Ts[c4 * 4 + 3][row] = (__bf16)v.w;
  }
  __syncthreads();
  #pragma unroll
  for (int i = 0; i < 2; i++) {
    int p = tid + 256 * i;            // 512 bf8 chunks: 64 n-rows x 8
    int n = p >> 3, kq = p & 7;
    bf8_t o = *reinterpret_cast<const bf8_t*>(&Ts[n][kq * 8]);
    *reinterpret_cast<bf8_t*>(wt + (size_t)z * 1024 * 1024 + (size_t)(n0 + n) * 1024 + k0 + kq * 8) = o;
  }
}

// ---------------------------------------------------------------------------
// 256x256-tile deep-pipelined GEMM (T2+T3+T4+T5):
//   C[8192 x 1024*NZ] = A[8192 x 1024] * Bt[z][n][k]^T
// 512 threads = 8 waves (2M x 4N); per-wave output 128x64; BK=64.
// LDS 128KB: A/B double-buffered as 8KB swizzled slices.
// Per K-tile: 2 sub-phases {vmcnt(4)+barrier; 12 ds_read_b128; issue 4
// glds16 for tile t+1 into buf^1; setprio(1); 32 MFMA; setprio(0)}.
// vmcnt never drains to 0 mid-loop (counted: next tile's 4 loads in flight).
// ---------------------------------------------------------------------------
template<bool OUT_BF16, int NZ>
__global__ __launch_bounds__(512, 2)
void gemm256_kernel(const __bf16* __restrict__ A, const __bf16* __restrict__ BtB,
                    void* __restrict__ Cp)
{
  using namespace abc;
  constexpr int K = 1024;
  constexpr int NZT = 4 * NZ;              // (n,z) combos per m-tile
  const int bflat = blockIdx.x;            // 32*4*NZ blocks (mult of 8)
  const int xcd = bflat & 7;
  const int j = bflat >> 3;
  const int m_local = j / NZT;             // 0..3
  const int nz = j % NZT;
  const int nt = nz & 3, z = nz >> 2;
  const int m0 = (xcd * 4 + m_local) * 256;
  const int n0 = nt * 256;
  const __bf16* Bt = BtB + (size_t)z * K * 1024;

  __shared__ __bf16 LA[2][4][4096];   // [dbuf][half*2+ksub][slice] (64KB)
  __shared__ __bf16 LB[2][4][4096];   // (64KB)

  const int tid = threadIdx.x;
  const int lane = tid & 63, wv = tid >> 6;
  const int wr = wv >> 2, wc = wv & 3;     // wave row 0..1, wave col 0..3
  const int quad = lane >> 4, l16 = lane & 15;
  const f4_t fzero = {0.f, 0.f, 0.f, 0.f};
  f4_t acc[8][4];
  #pragma unroll
  for (int fr = 0; fr < 8; fr++)
    #pragma unroll
    for (int fc = 0; fc < 4; fc++) acc[fr][fc] = fzero;

  // stage the 4 slices (A-half0, A-half1, B-half0, B-half1) of (kt, ks)
  auto issue4 = [&](int kt, int ks) {
    const int db = kt & 1;
    const int kcol = kt * 64 + ks * 32;
    stage_g(A  + (size_t)(m0 +   0) * K + kcol, K, &LA[db][0 + ks][0], tid);
    stage_g(A  + (size_t)(m0 + 128) * K + kcol, K, &LA[db][2 + ks][0], tid);
    stage_g(Bt + (size_t)(n0 +   0) * K + kcol, K, &LB[db][0 + ks][0], tid);
    stage_g(Bt + (size_t)(n0 + 128) * K + kcol, K, &LB[db][2 + ks][0], tid);
  };

  // prologue: both k-sub groups of tile 0 (8 loads/thread in flight)
  issue4(0, 0); issue4(0, 1);

  for (int kt = 0; kt < 16; kt++) {
    const int db = kt & 1;
    const bool last = (kt == 15);
    #pragma unroll
    for (int ks = 0; ks < 2; ks++) {
      // wait: the 4 slices this sub-phase reads have landed (all but the
      // newest 4 in-flight loads); barrier so every wave's portion is in.
      if (last && ks == 1) asm volatile("s_waitcnt vmcnt(0)\ns_barrier" ::: "memory");
      else                 asm volatile("s_waitcnt vmcnt(4)\ns_barrier" ::: "memory");
      // ds_read register fragments (2-way-conflict-free via stage_g swizzle)
      bf8_t af[8], bfv[4];
      #pragma unroll
      for (int fr = 0; fr < 8; fr++)
        af[fr] = bfrag_g(&LA[db][wr * 2 + ks][0], fr * 16 + l16, quad);
      #pragma unroll
      for (int fc = 0; fc < 4; fc++)
        bfv[fc] = bfrag_g(&LB[db][(wc >> 1) * 2 + ks][0], (wc & 1) * 64 + fc * 16 + l16, quad);
      // prefetch: same k-sub group of tile kt+1 into the other buffer
      // (its last readers were tile kt-1, retired before this barrier)
      if (!last) issue4(kt + 1, ks);
      __builtin_amdgcn_s_setprio(1);
      #pragma unroll
      for (int fr = 0; fr < 8; fr++)
        #pragma unroll
        for (int fc = 0; fc < 4; fc++)
          acc[fr][fc] = mfma16(af[fr], bfv[fc], acc[fr][fc]);
      __builtin_amdgcn_s_setprio(0);
    }
  }

  const int crow = m0 + wr * 128, ccol = n0 + wc * 64;
  if (OUT_BF16) {
    __bf16* C = (__bf16*)Cp + (size_t)z * BT * 1024;
    #pragma unroll
    for (int fr = 0; fr < 8; fr++)
      #pragma unroll
      for (int fc = 0; fc < 4; fc++)
        #pragma unroll
        for (int r = 0; r < 4; r++)
          C[(size_t)(crow + fr * 16 + quad * 4 + r) * 1024 + ccol + fc * 16 + l16] =
              (__bf16)acc[fr][fc][r];
  } else {
    float* C = (float*)Cp;
    #pragma unroll
    for (int fr = 0; fr < 8; fr++)
      #pragma unroll
      for (int fc = 0; fc < 4; fc++)
        #pragma unroll
        for (int r = 0; r < 4; r++)
          C[(size_t)(crow + fr * 16 + quad * 4 + r) * 1024 + ccol + fc * 16 + l16] =
              acc[fr][fc][r];
  }
}

// ---------------------------------------------------------------------------
// sg projection
// ---------------------------------------------------------------------------
__global__ __launch_bounds__(256)
void sg_kernel(const float* __restrict__ x, const float* __restrict__ sgw,
               float* __restrict__ sgl)
{
  using namespace abc;
  const int wvid = threadIdx.x >> 6, lane = threadIdx.x & 63;
  const int bt = blockIdx.x * 4 + wvid;
  const float* xr = x + (size_t)bt * 1024;
  float a0 = 0, a1 = 0, a2 = 0, a3 = 0;
  #pragma unroll 4
  for (int u = 0; u < 16; u++) {
    int i = u * 64 + lane;
    float xv = xr[i];
    float4 w = *reinterpret_cast<const float4*>(sgw + (size_t)i * 4);
    a0 += xv * w.x; a1 += xv * w.y; a2 += xv * w.z; a3 += xv * w.w;
  }
  #pragma unroll
  for (int off = 32; off > 0; off >>= 1) {
    a0 += __shfl_down(a0, off);
    a1 += __shfl_down(a1, off);
    a2 += __shfl_down(a2, off);
    a3 += __shfl_down(a3, off);
  }
  if (lane == 0) {
    const int b = bt >> 11, t = bt & (T - 1);
    float r[4] = {a0, a1, a2, a3};
    #pragma unroll
    for (int h = 0; h < 4; h++) {
      float v = r[h];
      float ls = fminf(v, 0.f) - log1pf(expf(-fabsf(v)));
      sgl[(size_t)(b * 4 + h) * T + t] = ls * (1.0f / GN);
    }
  }
}

// ---------------------------------------------------------------------------
// inclusive cumsum over T per (b,h)
// ---------------------------------------------------------------------------
__global__ __launch_bounds__(256)
void scan_kernel(const float* __restrict__ sgl, float* __restrict__ sgc)
{
  using namespace abc;
  const int bh = blockIdx.x;
  const float* in = sgl + (size_t)bh * T;
  float* out = sgc + (size_t)bh * T;
  __shared__ float part[256];
  const int tid = threadIdx.x;
  float v[8]; float s = 0.f;
  #pragma unroll
  for (int i = 0; i < 8; i++) { v[i] = in[tid * 8 + i]; s += v[i]; }
  part[tid] = s;
  __syncthreads();
  for (int off = 1; off < 256; off <<= 1) {
    float a = (tid >= off) ? part[tid - off] : 0.f;
    __syncthreads();
    part[tid] += a;
    __syncthreads();
  }
  float run = (tid > 0) ? part[tid - 1] : 0.f;
  #pragma unroll
  for (int i = 0; i < 8; i++) { run += v[i]; out[tid * 8 + i] = run; }
}

// ---------------------------------------------------------------------------
// prep: RoPE(q), RoPE(k)*exp(cumsum sg), s -> exp(clamp(s)) ; in-place on bf16
// ---------------------------------------------------------------------------
__global__ __launch_bounds__(256)
void prep_kernel(__bf16* __restrict__ q, __bf16* __restrict__ k,
                 __bf16* __restrict__ s, const float* __restrict__ sgc)
{
  using namespace abc;
  const int bt = blockIdx.x;
  const int b = bt >> 11, t = bt & (T - 1);
  const int tid = threadIdx.x;
  const size_t ro = (size_t)bt * 1024;
  #pragma unroll
  for (int i = 0; i < 2; i++) {
    int p = tid + 256 * i;          // 0..511 : h = p/128, d = p%128
    int h = p >> 7, d = p & 127;
    float inv = expf(-(float)d * (9.210340371976184f / 128.0f)); // 10000^(-d/128)
    float ang = (float)t * inv;
    float sn, cs;
    sincosf(ang, &sn, &cs);
    size_t base = ro + (size_t)h * 256 + d;
    float q1 = (float)q[base], q2 = (float)q[base + 128];
    q[base]       = (__bf16)(q1 * cs - q2 * sn);
    q[base + 128] = (__bf16)(q2 * cs + q1 * sn);
    float dec = expf(sgc[(size_t)(b * 4 + h) * T + t]);
    float k1 = (float)k[base], k2 = (float)k[base + 128];
    k[base]       = (__bf16)((k1 * cs - k2 * sn) * dec);
    k[base + 128] = (__bf16)((k2 * cs + k1 * sn) * dec);
  }
  #pragma unroll
  for (int i = 0; i < 4; i++) {
    int e = tid + 256 * i;
    float v = (float)s[ro + e];
    v = fminf(fmaxf(v, -32.f), 32.f);
    s[ro + e] = (__bf16)expf(v);
  }
}

// ---------------------------------------------------------------------------
// transpose chunks: [t=64][f=256] -> per-chunk [f=256][t=64]; dest layout is
// either row-major (KT, for chunkstate) or slice-major pre-swizzled (VT/AT,
// for coalesced attn staging). LDS XOR-swizzled.
// ---------------------------------------------------------------------------
template<bool NEW0, bool NEW1>
__global__ __launch_bounds__(256)
void transpose_kernel(const __bf16* __restrict__ s0, const __bf16* __restrict__ s1,
                      __bf16* __restrict__ d0, __bf16* __restrict__ d1)
{
  using namespace abc;
  const int c = blockIdx.x, bh = blockIdx.y, z = blockIdx.z;
  const int b = bh >> 2, h = bh & 3;
  const size_t R = (size_t)b * T + (size_t)c * CH;
  const int F = h * 256;
  const __bf16* src = z ? s1 : s0;
  __bf16* dst = (z ? d1 : d0) + ((size_t)bh * NC + c) * (256 * 64);
  const bool NEWL = z ? NEW1 : NEW0;
  __shared__ __bf16 L[256 * 64];
  const int tid = threadIdx.x;
  #pragma unroll
  for (int j = 0; j < 8; j++) {
    int p = tid + 256 * j;            // (t = p>>5, fc = p&31)
    int t = p >> 5, fc = p & 31;
    bf8_t v = *reinterpret_cast<const bf8_t*>(src + (R + t) * 1024 + F + fc * 8);
    const int sw = ((t >> 3) ^ (fc & 7)) * 8 + (t & 7);
    #pragma unroll
    for (int u = 0; u < 8; u++)
      L[(fc * 8 + u) * 64 + sw] = v[u];
  }
  __syncthreads();
  #pragma unroll
  for (int j = 0; j < 8; j++) {
    int p = tid + 256 * j;            // (f = p>>3, q = p&7)
    int f = p >> 3, q = p & 7;
    int phys = q ^ ((f >> 3) & 7);
    bf8_t o = *reinterpret_cast<const bf8_t*>(&L[f * 64 + phys * 8]);
    __bf16* daddr = NEWL ? slice_addr(dst, f, q)
                         : dst + (size_t)f * 64 + q * 8;
    *reinterpret_cast<bf8_t*>(daddr) = o;
  }
}

// ---------------------------------------------------------------------------
// per-chunk states. KT is row-major [f][t]; VT/AT are slice-major swizzled.
// HKc/HVc outputs are written slice-major swizzled (for coalesced attn
// staging; prefix_state is permutation-invariant).
// ---------------------------------------------------------------------------
__global__ __launch_bounds__(256)
void chunkstate_kernel(const __bf16* __restrict__ KT, const __bf16* __restrict__ VT,
                       const __bf16* __restrict__ AT,
                       __bf16* __restrict__ HKc, __bf16* __restrict__ HVc,
                       float* __restrict__ csA)
{
  using namespace abc;
  const int c = blockIdx.x, bh = blockIdx.y, part = blockIdx.z;
  const size_t TB = ((size_t)bh * NC + c) * (256 * 64);
  const bool isHV = part >= 2;
  const int p2 = part & 1;
  const __bf16* Aop = (isHV ? VT : AT) + TB;   // rows = out-dim (v or m); slice-major
  const __bf16* Bop = (isHV ? AT : KT) + TB;   // rows = out-col (m: slice-major | k: row-major)
  const int tid = threadIdx.x;
  if (part == 2) {
    float ssum = 0.f;
    #pragma unroll
    for (int u = 0; u < 8; u++) {
      bf8_t v = *reinterpret_cast<const bf8_t*>(slice_addr(AT + TB, tid, u));
      #pragma unroll
      for (int w = 0; w < 8; w++) ssum += (float)v[w];
    }
    csA[((size_t)bh * NC + c) * 256 + tid] = ssum;
  }
  const int lane = tid & 63, wvid = tid >> 6;
  const int quad = lane >> 4, l16 = lane & 15;
  const int row0 = p2 * 128 + wvid * 32;
  const f4_t fzero = {0.f, 0.f, 0.f, 0.f};
  f4_t acc[2][16];
  #pragma unroll
  for (int a = 0; a < 2; a++)
    #pragma unroll
    for (int ct = 0; ct < 16; ct++) acc[a][ct] = fzero;
  #pragma unroll
  for (int ks = 0; ks < 2; ks++) {
    const int cg = ks * 4 + quad;
    bf8_t af0 = *reinterpret_cast<const bf8_t*>(slice_addr(Aop, row0 + l16, cg));
    bf8_t af1 = *reinterpret_cast<const bf8_t*>(slice_addr(Aop, row0 + 16 + l16, cg));
    #pragma unroll
    for (int ct = 0; ct < 16; ct++) {
      bf8_t bv;
      if (isHV)
        bv = *reinterpret_cast<const bf8_t*>(slice_addr(Bop, ct * 16 + l16, cg));
      else
        bv = *reinterpret_cast<const bf8_t*>(Bop + (size_t)(ct * 16 + l16) * 64 + ks * 32 + quad * 8);
      acc[0][ct] = mfma16(af0, bv, acc[0][ct]);
      acc[1][ct] = mfma16(af1, bv, acc[1][ct]);
    }
  }
  __bf16* out = (isHV ? HVc : HKc) + ((size_t)bh * NC + c) * 65536;
  #pragma unroll
  for (int rt = 0; rt < 2; rt++)
    #pragma unroll
    for (int ct = 0; ct < 16; ct++)
      #pragma unroll
      for (int r = 0; r < 4; r++) {
        const int mg = row0 + rt * 16 + quad * 4 + r;   // out row 0..255
        const int n  = ct * 16 + l16;                    // out col 0..255
        *(slice_addr(out, mg, n >> 3) + (n & 7)) = (__bf16)acc[rt][ct][r];
      }
}

// ---------------------------------------------------------------------------
// in-place exclusive prefix over chunk axis of HKc/HVc (bf16, fp32 run)
// 16B vectorized; layout-agnostic (elementwise over the 65536-elem chunk).
// ---------------------------------------------------------------------------
__global__ __launch_bounds__(256)
void prefix_state_kernel(__bf16* __restrict__ HKc, __bf16* __restrict__ HVc)
{
  using namespace abc;
  const int bh = blockIdx.y;
  __bf16* base = (blockIdx.z ? HVc : HKc) + (size_t)bh * NC * 65536;
  const int e = (blockIdx.x * 256 + threadIdx.x) * 8;
  float run[8];
  #pragma unroll
  for (int u = 0; u < 8; u++) run[u] = 0.f;
  #pragma unroll 4
  for (int c = 0; c < NC; c++) {
    __bf16* p = base + (size_t)c * 65536 + e;
    bf8_t v = *reinterpret_cast<const bf8_t*>(p);
    bf8_t o;
    #pragma unroll
    for (int u = 0; u < 8; u++) { o[u] = (__bf16)run[u]; run[u] += (float)v[u]; }
    *reinterpret_cast<bf8_t*>(p) = o;
  }
}

__global__ __launch_bounds__(256)
void prefix_csa_kernel(float* __restrict__ csA)
{
  using namespace abc;
  const int bh = blockIdx.x, m = threadIdx.x;
  float run = 0.f;
  for (int c = 0; c < NC; c++) {
    float* p = csA + ((size_t)bh * NC + c) * 256 + m;
    float v = *p; *p = run; run += v;
  }
}

// ---------------------------------------------------------------------------
// main chunked ABC attention + fused RMSNorm/SiLU-gate epilogue
// one block per (chunk, bh). 48-slice schedule over a 4-deep 8KB ring.
// AT/HK/HV/VT slices are CONTIGUOUS in global (slice-major pre-swizzled
// layout) -> each stage is 2 coalesced 1KB bursts per wave. K/A slices
// remain row-major gathers.
// ---------------------------------------------------------------------------
__global__ __launch_bounds__(256)
void attn_kernel(const __bf16* __restrict__ qg, const __bf16* __restrict__ kg,
                 const __bf16* __restrict__ ag, const __bf16* __restrict__ gg,
                 const __bf16* __restrict__ ATp, const __bf16* __restrict__ VTp,
                 const __bf16* __restrict__ HKp, const __bf16* __restrict__ HVp,
                 const float* __restrict__ Zp, const float* __restrict__ gnw,
                 __bf16* __restrict__ yout)
{
  using namespace abc;
  const int c = blockIdx.x, bh = blockIdx.y;
  const int b = bh >> 2, h = bh & 3;
  const size_t R = (size_t)b * T + (size_t)c * CH;
  const int F = h * 256;
  const int tid = threadIdx.x;
  const int lane = tid & 63, wvid = tid >> 6;
  const int quad = lane >> 4, l16 = lane & 15;

  __shared__ __bf16 ST[4][4096];   // staging ring, 4 x 8 KB
  __shared__ __bf16 Ws[64][264];   // W = qv / SumA (per-wave strip)
  __shared__ __bf16 S1s[64][72];   // masked QK^T, later masked P (per-wave strip)
  __shared__ float zs[256];
  __shared__ float gns[256];

  const __bf16* atb = ATp + ((size_t)bh * NC + c) * (256 * 64);
  const __bf16* vtb = VTp + ((size_t)bh * NC + c) * (256 * 64);
  const __bf16* hkb = HKp + ((size_t)bh * NC + c) * 65536;
  const __bf16* hvb = HVp + ((size_t)bh * NC + c) * 65536;
  const __bf16* kbase = kg + R * 1024 + F;
  const __bf16* abase = ag + R * 1024 + F;

  zs[tid] = Zp[((size_t)bh * NC + c) * 256 + tid];
  gns[tid] = gnw[tid];
  __syncthreads();   // publish zs/gns

  // preload Q fragments (row = own strip row, all 8 k-groups)
  const __bf16* qrow = qg + (R + wvid * 16 + l16) * 1024 + F;
  bf8_t aq[8];
  #pragma unroll
  for (int ks = 0; ks < 8; ks++)
    aq[ks] = *reinterpret_cast<const bf8_t*>(qrow + ks * 32 + quad * 8);

  const f4_t fzero = {0.f, 0.f, 0.f, 0.f};

  // flat slice schedule (48 slices x 8KB, 2 loads/wave each):
  //   0..3   K   (scatter) | 4..7 AT (lin) | 8..23 HK (lin)
  //  24..27  A   (scatter) | 28..43 HV (lin) | 44..47 VT (lin)
  auto issue = [&](int s) {
    if (s >= 48) return;
    __bf16* buf = &ST[s & 3][0];
    if (s < 4) {
      stage<64>(kbase + (2 * s) * 32, 1024, buf, tid);
      stage<64>(kbase + (2 * s + 1) * 32, 1024, buf + 2048, tid);
    } else if (s < 8) {
      stage_lin(atb + (s - 4) * 4096, buf, tid);
    } else if (s < 24) {
      stage_lin(hkb + (s - 8) * 4096, buf, tid);
    } else if (s < 28) {
      int j = s - 24;
      stage<64>(abase + (2 * j) * 32, 1024, buf, tid);
      stage<64>(abase + (2 * j + 1) * 32, 1024, buf + 2048, tid);
    } else if (s < 44) {
      stage_lin(hvb + (s - 28) * 4096, buf, tid);
    } else {
      stage_lin(vtb + (s - 44) * 4096, buf, tid);
    }
  };

  // prologue: fill 3 ring buffers
  issue(0); issue(1); issue(2);

  // ---- phase A: S1 = Q K^T (slices 0..3) ----
  f4_t s1a[4];
  #pragma unroll
  for (int it = 0; it < 4; it++) s1a[it] = fzero;
  #pragma unroll
  for (int j = 0; j < 4; j++) {
    ring_pre(j);
    issue(j + 3);
    const __bf16* sl = &ST[j & 3][0];
    #pragma unroll
    for (int ks2 = 0; ks2 < 2; ks2++) {
      bf8_t a = aq[2 * j + ks2];
      const __bf16* sb = sl + ks2 * 2048;
      #pragma unroll
      for (int it = 0; it < 4; it++)
        s1a[it] = mfma16(a, bfrag(sb, it * 16 + l16, quad), s1a[it]);
    }
  }
  #pragma unroll
  for (int it = 0; it < 4; it++)
    #pragma unroll
    for (int r = 0; r < 4; r++) {
      int tl = wvid * 16 + quad * 4 + r;
      int il = it * 16 + l16;
      S1s[tl][il] = (il <= tl) ? (__bf16)s1a[it][r] : (__bf16)0.0f;
    }

  // ---- phase B: intra numerator + cumA (slices 4..7) ----
  f4_t aok[16], acum[16];
  #pragma unroll
  for (int mt = 0; mt < 16; mt++) { aok[mt] = fzero; acum[mt] = fzero; }
  #pragma unroll
  for (int j = 0; j < 4; j++) {
    int s = 4 + j, iks = j >> 1, rh = j & 1;
    ring_pre(s);
    issue(s + 3);
    const __bf16* sl = &ST[s & 3][0];
    bf8_t s1f = *reinterpret_cast<const bf8_t*>(&S1s[wvid * 16 + l16][iks * 32 + quad * 8]);
    bf8_t lf;
    #pragma unroll
    for (int u = 0; u < 8; u++)
      lf[u] = (iks * 32 + quad * 8 + u <= wvid * 16 + l16) ? (__bf16)1.0f : (__bf16)0.0f;
    #pragma unroll
    for (int m8 = 0; m8 < 8; m8++) {
      bf8_t bfa = bfrag(sl, m8 * 16 + l16, quad);
      aok[rh * 8 + m8]  = mfma16(s1f, bfa, aok[rh * 8 + m8]);
      acum[rh * 8 + m8] = mfma16(lf,  bfa, acum[rh * 8 + m8]);
    }
  }

  // ---- phase C: cross numerator Q @ HKpre (slices 8..23) ----
  #pragma unroll
  for (int j = 0; j < 16; j++) {
    int s = 8 + j, ks = j >> 1, rh = j & 1;
    ring_pre(s);
    issue(s + 3);
    const __bf16* sl = &ST[s & 3][0];
    #pragma unroll
    for (int m8 = 0; m8 < 8; m8++) {
      bf8_t bv = bfrag(sl, m8 * 16 + l16, quad);
      aok[rh * 8 + m8] = mfma16(aq[ks], bv, aok[rh * 8 + m8]);
    }
  }

  // ---- softmax over m ; W = qv / SumA (wave-private strip, no barrier) ----
  #pragma unroll
  for (int r = 0; r < 4; r++) {
    float ovv[16], sa[16];
    float mx = -3.0e38f;
    #pragma unroll
    for (int mt = 0; mt < 16; mt++) {
      sa[mt] = zs[mt * 16 + l16] + acum[mt][r];
      ovv[mt] = SCALE * aok[mt][r] / sa[mt];
      mx = fmaxf(mx, ovv[mt]);
    }
    #pragma unroll
    for (int off = 1; off < 16; off <<= 1) mx = fmaxf(mx, __shfl_xor(mx, off));
    float se = 0.f;
    #pragma unroll
    for (int mt = 0; mt < 16; mt++) { ovv[mt] = __expf(ovv[mt] - mx); se += ovv[mt]; }
    #pragma unroll
    for (int off = 1; off < 16; off <<= 1) se += __shfl_xor(se, off);
    float inv = 1.0f / se;
    int tl = wvid * 16 + quad * 4 + r;
    #pragma unroll
    for (int mt = 0; mt < 16; mt++)
      Ws[tl][mt * 16 + l16] = (__bf16)(ovv[mt] * inv / sa[mt]);
  }

  // ---- phase 4a: P = mask(W @ A^T) (slices 24..27) ----
  f4_t pacc[4];
  #pragma unroll
  for (int it = 0; it < 4; it++) pacc[it] = fzero;
  #pragma unroll
  for (int j = 0; j < 4; j++) {
    int s = 24 + j;
    ring_pre(s);
    issue(s + 3);
    const __bf16* sl = &ST[s & 3][0];
    #pragma unroll
    for (int ks2 = 0; ks2 < 2; ks2++) {
      int ks = 2 * j + ks2;
      bf8_t wf = *reinterpret_cast<const bf8_t*>(&Ws[wvid * 16 + l16][ks * 32 + quad * 8]);
      const __bf16* sb = sl + ks2 * 2048;
      #pragma unroll
      for (int it = 0; it < 4; it++)
        pacc[it] = mfma16(wf, bfrag(sb, it * 16 + l16, quad), pacc[it]);
    }
  }
  #pragma unroll
  for (int it = 0; it < 4; it++)
    #pragma unroll
    for (int r = 0; r < 4; r++) {
      int tl = wvid * 16 + quad * 4 + r;
      int il = it * 16 + l16;
      S1s[tl][il] = (il <= tl) ? (__bf16)pacc[it][r] : (__bf16)0.0f;
    }

  // ---- phase 4b-1: O = W @ HVpre^T (slices 28..43) ----
  f4_t oacc[16];
  #pragma unroll
  for (int vt = 0; vt < 16; vt++) oacc[vt] = fzero;
  #pragma unroll
  for (int j = 0; j < 16; j++) {
    int s = 28 + j, ks = j >> 1, rh = j & 1;
    ring_pre(s);
    issue(s + 3);
    const __bf16* sl = &ST[s & 3][0];
    bf8_t wf = *reinterpret_cast<const bf8_t*>(&Ws[wvid * 16 + l16][ks * 32 + quad * 8]);
    #pragma unroll
    for (int v8 = 0; v8 < 8; v8++) {
      bf8_t bv = bfrag(sl, v8 * 16 + l16, quad);
      oacc[rh * 8 + v8] = mfma16(wf, bv, oacc[rh * 8 + v8]);
    }
  }

  // ---- phase 4b-2: O += P @ V (slices 44..47) ----
  #pragma unroll
  for (int j = 0; j < 4; j++) {
    int s = 44 + j, iks = j >> 1, rh = j & 1;
    ring_pre(s);
    issue(s + 3);   // no-op (>= 48)
    const __bf16* sl = &ST[s & 3][0];
    bf8_t pf = *reinterpret_cast<const bf8_t*>(&S1s[wvid * 16 + l16][iks * 32 + quad * 8]);
    #pragma unroll
    for (int v8 = 0; v8 < 8; v8++) {
      bf8_t bvt = bfrag(sl, v8 * 16 + l16, quad);
      oacc[rh * 8 + v8] = mfma16(pf, bvt, oacc[rh * 8 + v8]);
    }
  }

  // ---- epilogue: fused RMSNorm * gn_w * g * sigmoid(g) -> y (bf16) ----
  #pragma unroll
  for (int r = 0; r < 4; r++) {
    float ss = 0.f;
    #pragma unroll
    for (int vt = 0; vt < 16; vt++) ss += oacc[vt][r] * oacc[vt][r];
    #pragma unroll
    for (int off = 1; off < 16; off <<= 1) ss += __shfl_xor(ss, off);
    float rinv = rsqrtf(ss * (1.0f / 256.0f) + EPS);
    int tl = wvid * 16 + quad * 4 + r;
    const __bf16* grow = gg + (R + tl) * 1024 + F;
    __bf16* yrow = yout + (R + tl) * 1024 + F;
    #pragma unroll
    for (int vt = 0; vt < 16; vt++) {
      int v = vt * 16 + l16;
      float gvl = (float)grow[v];
      float yv = oacc[vt][r] * rinv * gns[v] * gvl / (1.0f + __expf(-gvl));
      yrow[v] = (__bf16)yv;
    }
  }
}

// ---------------------------------------------------------------------------
// Workspace layout (MB), peak 253 MB:
//   0-16 q | 16-32 k | 32-48 v -> AT | 48-64 g | 64-80 a | 80-96 xb -> VT
//   96-97 sgl/sgc/csA | 97-161 HKc | 161-225 HVc | 225-237 wt
//   237-253 KT -> y_bf
// ---------------------------------------------------------------------------
extern "C" void kernel_launch(void* const* d_in, const int* in_sizes, int n_in,
                              void* d_out, int out_size, void* d_ws, size_t ws_size,
                              hipStream_t stream) {
  using namespace abc;
  (void)in_sizes; (void)n_in; (void)out_size; (void)ws_size;
  const float* x    = (const float*)d_in[0];
  const float* q_w  = (const float*)d_in[1];
  const float* k_w  = (const float*)d_in[2];
  const float* v_w  = (const float*)d_in[3];
  const float* g_w  = (const float*)d_in[4];
  const float* s_w  = (const float*)d_in[5];
  const float* sg_w = (const float*)d_in[6];
  const float* gn_w = (const float*)d_in[7];
  const float* o_w  = (const float*)d_in[8];
  float* out = (float*)d_out;

  char* ws = (char*)d_ws;
  const size_t PROJ = (size_t)BT * 1024;       // elements per projection
  __bf16* proj = (__bf16*)ws;
  __bf16* q_bf = proj + 0 * PROJ;
  __bf16* k_bf = proj + 1 * PROJ;
  __bf16* v_bf = proj + 2 * PROJ;              // -> AT after transpose1
  __bf16* g_bf = proj + 3 * PROJ;
  __bf16* a_bf = proj + 4 * PROJ;
  __bf16* xb   = proj + 5 * PROJ;              // -> VT after proj gemm
  float* sgl = (float*)(ws + (size_t)96 * 1024 * 1024);
  float* sgc = sgl + (size_t)BH * T;
  float* csA = sgc + (size_t)BH * T;           // 16*32*256 floats
  __bf16* HKc = (__bf16*)(ws + (size_t)97 * 1024 * 1024);   // 64MB
  __bf16* HVc = HKc + (size_t)BH * NC * 65536;               // 64MB
  __bf16* wt  = (__bf16*)(ws + (size_t)225 * 1024 * 1024);  // 12MB
  __bf16* KT  = (__bf16*)(ws + (size_t)237 * 1024 * 1024);  // 16MB
  __bf16* VT  = xb;                            // overlay (xb dead)
  __bf16* AT  = v_bf;                          // overlay (v dead)
  __bf16* y_bf = KT;                           // overlay (KT dead)

  dim3 blk(256);
  dim3 blk512(512);
  cvt_w_kernel<<<dim3(16, 16, 6), blk, 0, stream>>>(q_w, k_w, v_w, g_w, s_w, o_w, wt);
  cvt_x_kernel<<<dim3(BT * 1024 / (256 * 8)), blk, 0, stream>>>(x, xb);
  gemm256_kernel<true, 5><<<dim3(32 * 4 * 5), blk512, 0, stream>>>(xb, wt, proj);
  sg_kernel<<<dim3(BT / 4), blk, 0, stream>>>(x, sg_w, sgl);
  scan_kernel<<<dim3(BH), blk, 0, stream>>>(sgl, sgc);
  prep_kernel<<<dim3(BT), blk, 0, stream>>>(q_bf, k_bf, a_bf, sgc);
  transpose_kernel<false, true><<<dim3(NC, BH, 2), blk, 0, stream>>>(k_bf, v_bf, KT, VT);
  transpose_kernel<true, true><<<dim3(NC, BH, 1), blk, 0, stream>>>(a_bf, a_bf, AT, AT);
  chunkstate_kernel<<<dim3(NC, BH, 4), blk, 0, stream>>>(KT, VT, AT, HKc, HVc, csA);
  prefix_state_kernel<<<dim3(32, BH, 2), blk, 0, stream>>>(HKc, HVc);
  prefix_csa_kernel<<<dim3(BH), blk, 0, stream>>>(csA);
  attn_kernel<<<dim3(NC, BH), blk, 0, stream>>>(
      q_bf, k_bf, a_bf, g_bf, AT, VT, HKc, HVc, csA, gn_w, y_bf);
  gemm256_kernel<false, 1><<<dim3(32 * 4), blk512, 0, stream>>>(
      y_bf, wt + (size_t)5 * 1024 * 1024, out);
}

// Round 4
// 473.874 us; speedup vs baseline: 1.0888x; 1.0888x over previous
//
#include <hip/hip_runtime.h>
#include <hip/hip_bf16.h>
#include <stdint.h>
#include <stddef.h>
#include <math.h>

typedef __bf16 bf8_t __attribute__((ext_vector_type(8)));
typedef float  f4_t  __attribute__((ext_vector_type(4)));
typedef unsigned int u32;

#define DEV static __device__ __forceinline__

namespace abc {
constexpr int B = 4, T = 2048, D = 1024, H = 4;
constexpr int BT = B * T;          // 8192
constexpr int CH = 64;             // chunk length
constexpr int NC = T / CH;         // 32 chunks
constexpr int BH = B * H;          // 16
constexpr float SCALE = 0.0625f;   // DK^-0.5
constexpr float GN = 16.0f;
constexpr float EPS = 1e-5f;
}

DEV f4_t mfma16(bf8_t a, bf8_t b, f4_t c) {
  return __builtin_amdgcn_mfma_f32_16x16x32_bf16(a, b, c, 0, 0, 0);
}

// async global->LDS, 16B per lane; lds dest must be wave-uniform base (+lane*16)
DEV void glds16(const void* g, void* l) {
  __builtin_amdgcn_global_load_lds(
      (const __attribute__((address_space(1))) u32*)g,
      (__attribute__((address_space(3))) u32*)l, 16, 0, 0);
}

// ---------------------------------------------------------------------------
// Slice-major pre-swizzled layout for MFMA B-operand matrices.
// A matrix M[R][C] (R mult of 128, C mult of 32) is stored as slices
// s = (colchunk cg32 = col/32) x (rowhalf rh = row/128), each slice 4096
// elems (8KB): group p' = ((row&127)<<2) | (((col>>3)&3) ^ (row&3)),
// elem = slice*4096 + p'*8 + (col&7).
// KEY property: a wave's 64 bf8 fragment reads (rows m8*16+l16, col-group
// quad) of one slice form ONE CONTIGUOUS 1KB region -> fully-coalesced
// direct-from-global MFMA operand loads, no LDS round-trip needed.
// ---------------------------------------------------------------------------
DEV __bf16* slice_addr(__bf16* base, int row, int cg /*col/8*/) {
  return base + (((cg >> 2) * 2 + (row >> 7)) * 4096
               + ((((row & 127) << 2) | ((cg & 3) ^ (row & 3))) * 8));
}
DEV const __bf16* slice_addr(const __bf16* base, int row, int cg) {
  return base + (((cg >> 2) * 2 + (row >> 7)) * 4096
               + ((((row & 127) << 2) | ((cg & 3) ^ (row & 3))) * 8));
}

// ---------------------------------------------------------------------------
// GEMM-local swizzle: XOR uses (row>>1)&3 so the 16-lane ds_read_b128 pattern
// (rows fr*16+l16, fixed quad) spreads across 8 distinct 16B slots (2-way
// conflict = free). 512-thread staging: 1 glds16/thread per 8KB slice.
// ---------------------------------------------------------------------------
DEV void stage_g(const __bf16* __restrict__ g, int S, __bf16* lds, int tid) {
  int m = tid >> 2;
  int q = (tid & 3) ^ ((m >> 1) & 3);
  glds16(g + (size_t)m * S + q * 8, lds + (tid & ~63) * 8);
}
DEV bf8_t bfrag_g(const __bf16* sl, int m, int quad) {
  return *reinterpret_cast<const bf8_t*>(sl + m * 32 + (((quad ^ (m >> 1)) & 3) << 3));
}

// ---------------------------------------------------------------------------
// x fp32 -> bf16 (row-major unchanged). 8 elems/thread.
// ---------------------------------------------------------------------------
__global__ __launch_bounds__(256)
void cvt_x_kernel(const float* __restrict__ x, __bf16* __restrict__ xb)
{
  const int idx = blockIdx.x * 256 + threadIdx.x;   // 1M threads total
  const float4* src = reinterpret_cast<const float4*>(x);
  float4 a = src[(size_t)idx * 2];
  float4 b = src[(size_t)idx * 2 + 1];
  bf8_t o;
  o[0] = (__bf16)a.x; o[1] = (__bf16)a.y; o[2] = (__bf16)a.z; o[3] = (__bf16)a.w;
  o[4] = (__bf16)b.x; o[5] = (__bf16)b.y; o[6] = (__bf16)b.z; o[7] = (__bf16)b.w;
  reinterpret_cast<bf8_t*>(xb)[idx] = o;
}

// ---------------------------------------------------------------------------
// weight fp32 [k][n] -> bf16 [n][k] (transpose), 64x64 tiles, 6 weights
// ---------------------------------------------------------------------------
__global__ __launch_bounds__(256)
void cvt_w_kernel(const float* __restrict__ w0, const float* __restrict__ w1,
                  const float* __restrict__ w2, const float* __restrict__ w3,
                  const float* __restrict__ w4, const float* __restrict__ w5,
                  __bf16* __restrict__ wt)
{
  const int z = blockIdx.z;
  const float* W = (z == 0) ? w0 : (z == 1) ? w1 : (z == 2) ? w2
                 : (z == 3) ? w3 : (z == 4) ? w4 : w5;
  const int n0 = blockIdx.x * 64, k0 = blockIdx.y * 64;
  __shared__ __bf16 Ts[64][72];
  const int tid = threadIdx.x;
  #pragma unroll
  for (int i = 0; i < 4; i++) {
    int p = tid + 256 * i;            // 1024 float4 chunks: 64 k-rows x 16
    int row = p >> 4, c4 = p & 15;
    float4 v = *reinterpret_cast<const float4*>(W + (size_t)(k0 + row) * 1024 + n0 + c4 * 4);
    Ts[c4 * 4 + 0][row] = (__bf16)v.x;
    Ts[c4 * 4 + 1][row] = (__bf16)v.y;
    Ts[c4 * 4 + 2][row] = (__bf16)v.z;
    Ts[c4 * 4 + 3][row] = (__bf16)v.w;
  }
  __syncthreads();
  #pragma unroll
  for (int i = 0; i < 2; i++) {
    int p = tid + 256 * i;            // 512 bf8 chunks: 64 n-rows x 8
    int n = p >> 3, kq = p & 7;
    bf8_t o = *reinterpret_cast<const bf8_t*>(&Ts[n][kq * 8]);
    *reinterpret_cast<bf8_t*>(wt + (size_t)z * 1024 * 1024 + (size_t)(n0 + n) * 1024 + k0 + kq * 8) = o;
  }
}

// ---------------------------------------------------------------------------
// 256x256-tile deep-pipelined GEMM (T2+T3+T4+T5):
//   C[8192 x 1024*NZ] = A[8192 x 1024] * Bt[z][n][k]^T
// 512 threads = 8 waves (2M x 4N); per-wave output 128x64; BK=64.
// LDS 128KB: A/B double-buffered as 8KB swizzled slices.
// Per K-tile: 2 sub-phases {vmcnt(4)+barrier; 12 ds_read_b128; issue 4
// glds16 for tile t+1 into buf^1; setprio(1); 32 MFMA; setprio(0)}.
// vmcnt never drains to 0 mid-loop.
// ---------------------------------------------------------------------------
template<bool OUT_BF16, int NZ>
__global__ __launch_bounds__(512, 2)
void gemm256_kernel(const __bf16* __restrict__ A, const __bf16* __restrict__ BtB,
                    void* __restrict__ Cp)
{
  using namespace abc;
  constexpr int K = 1024;
  constexpr int NZT = 4 * NZ;              // (n,z) combos per m-tile
  const int bflat = blockIdx.x;            // 32*4*NZ blocks (mult of 8)
  const int xcd = bflat & 7;
  const int j = bflat >> 3;
  const int m_local = j / NZT;             // 0..3
  const int nz = j % NZT;
  const int nt = nz & 3, z = nz >> 2;
  const int m0 = (xcd * 4 + m_local) * 256;
  const int n0 = nt * 256;
  const __bf16* Bt = BtB + (size_t)z * K * 1024;

  __shared__ __bf16 LA[2][4][4096];   // [dbuf][half*2+ksub][slice] (64KB)
  __shared__ __bf16 LB[2][4][4096];   // (64KB)

  const int tid = threadIdx.x;
  const int lane = tid & 63, wv = tid >> 6;
  const int wr = wv >> 2, wc = wv & 3;     // wave row 0..1, wave col 0..3
  const int quad = lane >> 4, l16 = lane & 15;
  const f4_t fzero = {0.f, 0.f, 0.f, 0.f};
  f4_t acc[8][4];
  #pragma unroll
  for (int fr = 0; fr < 8; fr++)
    #pragma unroll
    for (int fc = 0; fc < 4; fc++) acc[fr][fc] = fzero;

  auto issue4 = [&](int kt, int ks) {
    const int db = kt & 1;
    const int kcol = kt * 64 + ks * 32;
    stage_g(A  + (size_t)(m0 +   0) * K + kcol, K, &LA[db][0 + ks][0], tid);
    stage_g(A  + (size_t)(m0 + 128) * K + kcol, K, &LA[db][2 + ks][0], tid);
    stage_g(Bt + (size_t)(n0 +   0) * K + kcol, K, &LB[db][0 + ks][0], tid);
    stage_g(Bt + (size_t)(n0 + 128) * K + kcol, K, &LB[db][2 + ks][0], tid);
  };

  issue4(0, 0); issue4(0, 1);

  for (int kt = 0; kt < 16; kt++) {
    const int db = kt & 1;
    const bool last = (kt == 15);
    #pragma unroll
    for (int ks = 0; ks < 2; ks++) {
      if (last && ks == 1) asm volatile("s_waitcnt vmcnt(0)\ns_barrier" ::: "memory");
      else                 asm volatile("s_waitcnt vmcnt(4)\ns_barrier" ::: "memory");
      bf8_t af[8], bfv[4];
      #pragma unroll
      for (int fr = 0; fr < 8; fr++)
        af[fr] = bfrag_g(&LA[db][wr * 2 + ks][0], fr * 16 + l16, quad);
      #pragma unroll
      for (int fc = 0; fc < 4; fc++)
        bfv[fc] = bfrag_g(&LB[db][(wc >> 1) * 2 + ks][0], (wc & 1) * 64 + fc * 16 + l16, quad);
      if (!last) issue4(kt + 1, ks);
      __builtin_amdgcn_s_setprio(1);
      #pragma unroll
      for (int fr = 0; fr < 8; fr++)
        #pragma unroll
        for (int fc = 0; fc < 4; fc++)
          acc[fr][fc] = mfma16(af[fr], bfv[fc], acc[fr][fc]);
      __builtin_amdgcn_s_setprio(0);
    }
  }

  const int crow = m0 + wr * 128, ccol = n0 + wc * 64;
  if (OUT_BF16) {
    __bf16* C = (__bf16*)Cp + (size_t)z * BT * 1024;
    #pragma unroll
    for (int fr = 0; fr < 8; fr++)
      #pragma unroll
      for (int fc = 0; fc < 4; fc++)
        #pragma unroll
        for (int r = 0; r < 4; r++)
          C[(size_t)(crow + fr * 16 + quad * 4 + r) * 1024 + ccol + fc * 16 + l16] =
              (__bf16)acc[fr][fc][r];
  } else {
    float* C = (float*)Cp;
    #pragma unroll
    for (int fr = 0; fr < 8; fr++)
      #pragma unroll
      for (int fc = 0; fc < 4; fc++)
        #pragma unroll
        for (int r = 0; r < 4; r++)
          C[(size_t)(crow + fr * 16 + quad * 4 + r) * 1024 + ccol + fc * 16 + l16] =
              acc[fr][fc][r];
  }
}

// ---------------------------------------------------------------------------
// sg projection
// ---------------------------------------------------------------------------
__global__ __launch_bounds__(256)
void sg_kernel(const float* __restrict__ x, const float* __restrict__ sgw,
               float* __restrict__ sgl)
{
  using namespace abc;
  const int wvid = threadIdx.x >> 6, lane = threadIdx.x & 63;
  const int bt = blockIdx.x * 4 + wvid;
  const float* xr = x + (size_t)bt * 1024;
  float a0 = 0, a1 = 0, a2 = 0, a3 = 0;
  #pragma unroll 4
  for (int u = 0; u < 16; u++) {
    int i = u * 64 + lane;
    float xv = xr[i];
    float4 w = *reinterpret_cast<const float4*>(sgw + (size_t)i * 4);
    a0 += xv * w.x; a1 += xv * w.y; a2 += xv * w.z; a3 += xv * w.w;
  }
  #pragma unroll
  for (int off = 32; off > 0; off >>= 1) {
    a0 += __shfl_down(a0, off);
    a1 += __shfl_down(a1, off);
    a2 += __shfl_down(a2, off);
    a3 += __shfl_down(a3, off);
  }
  if (lane == 0) {
    const int b = bt >> 11, t = bt & (T - 1);
    float r[4] = {a0, a1, a2, a3};
    #pragma unroll
    for (int h = 0; h < 4; h++) {
      float v = r[h];
      float ls = fminf(v, 0.f) - log1pf(expf(-fabsf(v)));
      sgl[(size_t)(b * 4 + h) * T + t] = ls * (1.0f / GN);
    }
  }
}

// ---------------------------------------------------------------------------
// inclusive cumsum over T per (b,h)
// ---------------------------------------------------------------------------
__global__ __launch_bounds__(256)
void scan_kernel(const float* __restrict__ sgl, float* __restrict__ sgc)
{
  using namespace abc;
  const int bh = blockIdx.x;
  const float* in = sgl + (size_t)bh * T;
  float* out = sgc + (size_t)bh * T;
  __shared__ float part[256];
  const int tid = threadIdx.x;
  float v[8]; float s = 0.f;
  #pragma unroll
  for (int i = 0; i < 8; i++) { v[i] = in[tid * 8 + i]; s += v[i]; }
  part[tid] = s;
  __syncthreads();
  for (int off = 1; off < 256; off <<= 1) {
    float a = (tid >= off) ? part[tid - off] : 0.f;
    __syncthreads();
    part[tid] += a;
    __syncthreads();
  }
  float run = (tid > 0) ? part[tid - 1] : 0.f;
  #pragma unroll
  for (int i = 0; i < 8; i++) { run += v[i]; out[tid * 8 + i] = run; }
}

// ---------------------------------------------------------------------------
// prep: RoPE(q), RoPE(k)*exp(cumsum sg), s -> exp(clamp(s)) ; in-place on bf16
// ---------------------------------------------------------------------------
__global__ __launch_bounds__(256)
void prep_kernel(__bf16* __restrict__ q, __bf16* __restrict__ k,
                 __bf16* __restrict__ s, const float* __restrict__ sgc)
{
  using namespace abc;
  const int bt = blockIdx.x;
  const int b = bt >> 11, t = bt & (T - 1);
  const int tid = threadIdx.x;
  const size_t ro = (size_t)bt * 1024;
  #pragma unroll
  for (int i = 0; i < 2; i++) {
    int p = tid + 256 * i;          // 0..511 : h = p/128, d = p%128
    int h = p >> 7, d = p & 127;
    float inv = expf(-(float)d * (9.210340371976184f / 128.0f)); // 10000^(-d/128)
    float ang = (float)t * inv;
    float sn, cs;
    sincosf(ang, &sn, &cs);
    size_t base = ro + (size_t)h * 256 + d;
    float q1 = (float)q[base], q2 = (float)q[base + 128];
    q[base]       = (__bf16)(q1 * cs - q2 * sn);
    q[base + 128] = (__bf16)(q2 * cs + q1 * sn);
    float dec = expf(sgc[(size_t)(b * 4 + h) * T + t]);
    float k1 = (float)k[base], k2 = (float)k[base + 128];
    k[base]       = (__bf16)((k1 * cs - k2 * sn) * dec);
    k[base + 128] = (__bf16)((k2 * cs + k1 * sn) * dec);
  }
  #pragma unroll
  for (int i = 0; i < 4; i++) {
    int e = tid + 256 * i;
    float v = (float)s[ro + e];
    v = fminf(fmaxf(v, -32.f), 32.f);
    s[ro + e] = (__bf16)expf(v);
  }
}

// ---------------------------------------------------------------------------
// transpose chunks: [t=64][f=256] -> per-chunk [f=256][t=64]; dest layout is
// either row-major (KT, for chunkstate) or slice-major pre-swizzled (VT/AT).
// ---------------------------------------------------------------------------
template<bool NEW0, bool NEW1>
__global__ __launch_bounds__(256)
void transpose_kernel(const __bf16* __restrict__ s0, const __bf16* __restrict__ s1,
                      __bf16* __restrict__ d0, __bf16* __restrict__ d1)
{
  using namespace abc;
  const int c = blockIdx.x, bh = blockIdx.y, z = blockIdx.z;
  const int b = bh >> 2, h = bh & 3;
  const size_t R = (size_t)b * T + (size_t)c * CH;
  const int F = h * 256;
  const __bf16* src = z ? s1 : s0;
  __bf16* dst = (z ? d1 : d0) + ((size_t)bh * NC + c) * (256 * 64);
  const bool NEWL = z ? NEW1 : NEW0;
  __shared__ __bf16 L[256 * 64];
  const int tid = threadIdx.x;
  #pragma unroll
  for (int j = 0; j < 8; j++) {
    int p = tid + 256 * j;            // (t = p>>5, fc = p&31)
    int t = p >> 5, fc = p & 31;
    bf8_t v = *reinterpret_cast<const bf8_t*>(src + (R + t) * 1024 + F + fc * 8);
    const int sw = ((t >> 3) ^ (fc & 7)) * 8 + (t & 7);
    #pragma unroll
    for (int u = 0; u < 8; u++)
      L[(fc * 8 + u) * 64 + sw] = v[u];
  }
  __syncthreads();
  #pragma unroll
  for (int j = 0; j < 8; j++) {
    int p = tid + 256 * j;            // (f = p>>3, q = p&7)
    int f = p >> 3, q = p & 7;
    int phys = q ^ ((f >> 3) & 7);
    bf8_t o = *reinterpret_cast<const bf8_t*>(&L[f * 64 + phys * 8]);
    __bf16* daddr = NEWL ? slice_addr(dst, f, q)
                         : dst + (size_t)f * 64 + q * 8;
    *reinterpret_cast<bf8_t*>(daddr) = o;
  }
}

// ---------------------------------------------------------------------------
// per-chunk states. KT is row-major [f][t]; VT/AT are slice-major swizzled.
// HKc/HVc outputs are written slice-major swizzled.
// ---------------------------------------------------------------------------
__global__ __launch_bounds__(256)
void chunkstate_kernel(const __bf16* __restrict__ KT, const __bf16* __restrict__ VT,
                       const __bf16* __restrict__ AT,
                       __bf16* __restrict__ HKc, __bf16* __restrict__ HVc,
                       float* __restrict__ csA)
{
  using namespace abc;
  const int c = blockIdx.x, bh = blockIdx.y, part = blockIdx.z;
  const size_t TB = ((size_t)bh * NC + c) * (256 * 64);
  const bool isHV = part >= 2;
  const int p2 = part & 1;
  const __bf16* Aop = (isHV ? VT : AT) + TB;   // rows = out-dim (v or m); slice-major
  const __bf16* Bop = (isHV ? AT : KT) + TB;   // rows = out-col (m: slice-major | k: row-major)
  const int tid = threadIdx.x;
  if (part == 2) {
    float ssum = 0.f;
    #pragma unroll
    for (int u = 0; u < 8; u++) {
      bf8_t v = *reinterpret_cast<const bf8_t*>(slice_addr(AT + TB, tid, u));
      #pragma unroll
      for (int w = 0; w < 8; w++) ssum += (float)v[w];
    }
    csA[((size_t)bh * NC + c) * 256 + tid] = ssum;
  }
  const int lane = tid & 63, wvid = tid >> 6;
  const int quad = lane >> 4, l16 = lane & 15;
  const int row0 = p2 * 128 + wvid * 32;
  const f4_t fzero = {0.f, 0.f, 0.f, 0.f};
  f4_t acc[2][16];
  #pragma unroll
  for (int a = 0; a < 2; a++)
    #pragma unroll
    for (int ct = 0; ct < 16; ct++) acc[a][ct] = fzero;
  #pragma unroll
  for (int ks = 0; ks < 2; ks++) {
    const int cg = ks * 4 + quad;
    bf8_t af0 = *reinterpret_cast<const bf8_t*>(slice_addr(Aop, row0 + l16, cg));
    bf8_t af1 = *reinterpret_cast<const bf8_t*>(slice_addr(Aop, row0 + 16 + l16, cg));
    #pragma unroll
    for (int ct = 0; ct < 16; ct++) {
      bf8_t bv;
      if (isHV)
        bv = *reinterpret_cast<const bf8_t*>(slice_addr(Bop, ct * 16 + l16, cg));
      else
        bv = *reinterpret_cast<const bf8_t*>(Bop + (size_t)(ct * 16 + l16) * 64 + ks * 32 + quad * 8);
      acc[0][ct] = mfma16(af0, bv, acc[0][ct]);
      acc[1][ct] = mfma16(af1, bv, acc[1][ct]);
    }
  }
  __bf16* out = (isHV ? HVc : HKc) + ((size_t)bh * NC + c) * 65536;
  #pragma unroll
  for (int rt = 0; rt < 2; rt++)
    #pragma unroll
    for (int ct = 0; ct < 16; ct++)
      #pragma unroll
      for (int r = 0; r < 4; r++) {
        const int mg = row0 + rt * 16 + quad * 4 + r;   // out row 0..255
        const int n  = ct * 16 + l16;                    // out col 0..255
        *(slice_addr(out, mg, n >> 3) + (n & 7)) = (__bf16)acc[rt][ct][r];
      }
}

// ---------------------------------------------------------------------------
// in-place exclusive prefix over chunk axis of HKc/HVc (bf16, fp32 run)
// ---------------------------------------------------------------------------
__global__ __launch_bounds__(256)
void prefix_state_kernel(__bf16* __restrict__ HKc, __bf16* __restrict__ HVc)
{
  using namespace abc;
  const int bh = blockIdx.y;
  __bf16* base = (blockIdx.z ? HVc : HKc) + (size_t)bh * NC * 65536;
  const int e = (blockIdx.x * 256 + threadIdx.x) * 8;
  float run[8];
  #pragma unroll
  for (int u = 0; u < 8; u++) run[u] = 0.f;
  #pragma unroll 4
  for (int c = 0; c < NC; c++) {
    __bf16* p = base + (size_t)c * 65536 + e;
    bf8_t v = *reinterpret_cast<const bf8_t*>(p);
    bf8_t o;
    #pragma unroll
    for (int u = 0; u < 8; u++) { o[u] = (__bf16)run[u]; run[u] += (float)v[u]; }
    *reinterpret_cast<bf8_t*>(p) = o;
  }
}

__global__ __launch_bounds__(256)
void prefix_csa_kernel(float* __restrict__ csA)
{
  using namespace abc;
  const int bh = blockIdx.x, m = threadIdx.x;
  float run = 0.f;
  for (int c = 0; c < NC; c++) {
    float* p = csA + ((size_t)bh * NC + c) * 256 + m;
    float v = *p; *p = run; run += v;
  }
}

// ---------------------------------------------------------------------------
// main chunked ABC attention + fused RMSNorm/SiLU-gate epilogue.
// NO LDS STAGING: every MFMA B-fragment is loaded straight from global into
// VGPRs (slice-major operands -> a wave's 64 fragment loads form ONE
// contiguous 1KB burst; row-major K/A -> 16x64B, no waste). No barriers, no
// vmcnt choreography: waves are fully independent, the compiler
// software-pipelines loads against MFMAs. Intra-block 4x reuse is served by
// L2 (~1.7GB aggregate at 34.5TB/s ~ 25us). LDS keeps only the wave-private
// Ws/S1s strips + zs/gns (45KB -> 2-3 blocks/CU).
// ---------------------------------------------------------------------------
__global__ __launch_bounds__(256)
void attn_kernel(const __bf16* __restrict__ qg, const __bf16* __restrict__ kg,
                 const __bf16* __restrict__ ag, const __bf16* __restrict__ gg,
                 const __bf16* __restrict__ ATp, const __bf16* __restrict__ VTp,
                 const __bf16* __restrict__ HKp, const __bf16* __restrict__ HVp,
                 const float* __restrict__ Zp, const float* __restrict__ gnw,
                 __bf16* __restrict__ yout)
{
  using namespace abc;
  const int c = blockIdx.x, bh = blockIdx.y;
  const int b = bh >> 2, h = bh & 3;
  const size_t R = (size_t)b * T + (size_t)c * CH;
  const int F = h * 256;
  const int tid = threadIdx.x;
  const int lane = tid & 63, wvid = tid >> 6;
  const int quad = lane >> 4, l16 = lane & 15;

  __shared__ __bf16 Ws[64][264];   // W = qv / SumA (per-wave strip)
  __shared__ __bf16 S1s[64][72];   // masked QK^T, later masked P (per-wave strip)
  __shared__ float zs[256];
  __shared__ float gns[256];

  const __bf16* atb = ATp + ((size_t)bh * NC + c) * (256 * 64);
  const __bf16* vtb = VTp + ((size_t)bh * NC + c) * (256 * 64);
  const __bf16* hkb = HKp + ((size_t)bh * NC + c) * 65536;
  const __bf16* hvb = HVp + ((size_t)bh * NC + c) * 65536;
  const __bf16* kbase = kg + R * 1024 + F;
  const __bf16* abase = ag + R * 1024 + F;

  zs[tid] = Zp[((size_t)bh * NC + c) * 256 + tid];
  gns[tid] = gnw[tid];
  __syncthreads();   // publish zs/gns (the only block-wide sync)

  // per-lane element offset inside an 8KB slice for fragment reads:
  // row = m8*16 + l16, colgroup = quad  ->  m8*512 + lsw
  const int lsw = l16 * 32 + ((quad ^ (l16 & 3)) << 3);
  const int rowoff = l16 * 1024 + quad * 8;   // row-major K/A fragment base

  // preload Q fragments (row = own strip row, all 8 k-groups)
  const __bf16* qrow = qg + (R + wvid * 16 + l16) * 1024 + F;
  bf8_t aq[8];
  #pragma unroll
  for (int ks = 0; ks < 8; ks++)
    aq[ks] = *reinterpret_cast<const bf8_t*>(qrow + ks * 32 + quad * 8);

  const f4_t fzero = {0.f, 0.f, 0.f, 0.f};

  // ---- phase A: S1 = Q K^T ----
  f4_t s1a[4];
  #pragma unroll
  for (int it = 0; it < 4; it++) s1a[it] = fzero;
  #pragma unroll
  for (int ks = 0; ks < 8; ks++) {
    #pragma unroll
    for (int it = 0; it < 4; it++) {
      bf8_t bk = *reinterpret_cast<const bf8_t*>(kbase + it * 16 * 1024 + rowoff + ks * 32);
      s1a[it] = mfma16(aq[ks], bk, s1a[it]);
    }
  }
  #pragma unroll
  for (int it = 0; it < 4; it++)
    #pragma unroll
    for (int r = 0; r < 4; r++) {
      int tl = wvid * 16 + quad * 4 + r;
      int il = it * 16 + l16;
      S1s[tl][il] = (il <= tl) ? (__bf16)s1a[it][r] : (__bf16)0.0f;
    }

  // ---- phase B: intra numerator + cumA (AT, slice-major) ----
  f4_t aok[16], acum[16];
  #pragma unroll
  for (int mt = 0; mt < 16; mt++) { aok[mt] = fzero; acum[mt] = fzero; }
  #pragma unroll
  for (int iks = 0; iks < 2; iks++) {
    bf8_t s1f = *reinterpret_cast<const bf8_t*>(&S1s[wvid * 16 + l16][iks * 32 + quad * 8]);
    bf8_t lf;
    #pragma unroll
    for (int u = 0; u < 8; u++)
      lf[u] = (iks * 32 + quad * 8 + u <= wvid * 16 + l16) ? (__bf16)1.0f : (__bf16)0.0f;
    #pragma unroll
    for (int rh = 0; rh < 2; rh++) {
      #pragma unroll
      for (int m8 = 0; m8 < 8; m8++) {
        bf8_t bfa = *reinterpret_cast<const bf8_t*>(atb + (iks * 2 + rh) * 4096 + m8 * 512 + lsw);
        aok[rh * 8 + m8]  = mfma16(s1f, bfa, aok[rh * 8 + m8]);
        acum[rh * 8 + m8] = mfma16(lf,  bfa, acum[rh * 8 + m8]);
      }
    }
  }

  // ---- phase C: cross numerator Q @ HKpre (slice-major) ----
  #pragma unroll
  for (int ks = 0; ks < 8; ks++) {
    #pragma unroll
    for (int rh = 0; rh < 2; rh++) {
      #pragma unroll
      for (int m8 = 0; m8 < 8; m8++) {
        bf8_t bv = *reinterpret_cast<const bf8_t*>(hkb + (ks * 2 + rh) * 4096 + m8 * 512 + lsw);
        aok[rh * 8 + m8] = mfma16(aq[ks], bv, aok[rh * 8 + m8]);
      }
    }
  }

  // ---- softmax over m ; W = qv / SumA (wave-private strip) ----
  #pragma unroll
  for (int r = 0; r < 4; r++) {
    float ovv[16], sa[16];
    float mx = -3.0e38f;
    #pragma unroll
    for (int mt = 0; mt < 16; mt++) {
      sa[mt] = zs[mt * 16 + l16] + acum[mt][r];
      ovv[mt] = SCALE * aok[mt][r] / sa[mt];
      mx = fmaxf(mx, ovv[mt]);
    }
    #pragma unroll
    for (int off = 1; off < 16; off <<= 1) mx = fmaxf(mx, __shfl_xor(mx, off));
    float se = 0.f;
    #pragma unroll
    for (int mt = 0; mt < 16; mt++) { ovv[mt] = __expf(ovv[mt] - mx); se += ovv[mt]; }
    #pragma unroll
    for (int off = 1; off < 16; off <<= 1) se += __shfl_xor(se, off);
    float inv = 1.0f / se;
    int tl = wvid * 16 + quad * 4 + r;
    #pragma unroll
    for (int mt = 0; mt < 16; mt++)
      Ws[tl][mt * 16 + l16] = (__bf16)(ovv[mt] * inv / sa[mt]);
  }

  // ---- phase 4a: P = mask(W @ A^T) (row-major A) ----
  f4_t pacc[4];
  #pragma unroll
  for (int it = 0; it < 4; it++) pacc[it] = fzero;
  #pragma unroll
  for (int ks = 0; ks < 8; ks++) {
    bf8_t wf = *reinterpret_cast<const bf8_t*>(&Ws[wvid * 16 + l16][ks * 32 + quad * 8]);
    #pragma unroll
    for (int it = 0; it < 4; it++) {
      bf8_t ba = *reinterpret_cast<const bf8_t*>(abase + it * 16 * 1024 + rowoff + ks * 32);
      pacc[it] = mfma16(wf, ba, pacc[it]);
    }
  }
  #pragma unroll
  for (int it = 0; it < 4; it++)
    #pragma unroll
    for (int r = 0; r < 4; r++) {
      int tl = wvid * 16 + quad * 4 + r;
      int il = it * 16 + l16;
      S1s[tl][il] = (il <= tl) ? (__bf16)pacc[it][r] : (__bf16)0.0f;
    }

  // ---- phase 4b-1: O = W @ HVpre^T (slice-major) ----
  f4_t oacc[16];
  #pragma unroll
  for (int vt = 0; vt < 16; vt++) oacc[vt] = fzero;
  #pragma unroll
  for (int ks = 0; ks < 8; ks++) {
    bf8_t wf = *reinterpret_cast<const bf8_t*>(&Ws[wvid * 16 + l16][ks * 32 + quad * 8]);
    #pragma unroll
    for (int rh = 0; rh < 2; rh++) {
      #pragma unroll
      for (int v8 = 0; v8 < 8; v8++) {
        bf8_t bv = *reinterpret_cast<const bf8_t*>(hvb + (ks * 2 + rh) * 4096 + v8 * 512 + lsw);
        oacc[rh * 8 + v8] = mfma16(wf, bv, oacc[rh * 8 + v8]);
      }
    }
  }

  // ---- phase 4b-2: O += P @ V (slice-major VT) ----
  #pragma unroll
  for (int iks = 0; iks < 2; iks++) {
    bf8_t pf = *reinterpret_cast<const bf8_t*>(&S1s[wvid * 16 + l16][iks * 32 + quad * 8]);
    #pragma unroll
    for (int rh = 0; rh < 2; rh++) {
      #pragma unroll
      for (int v8 = 0; v8 < 8; v8++) {
        bf8_t bvt = *reinterpret_cast<const bf8_t*>(vtb + (iks * 2 + rh) * 4096 + v8 * 512 + lsw);
        oacc[rh * 8 + v8] = mfma16(pf, bvt, oacc[rh * 8 + v8]);
      }
    }
  }

  // ---- epilogue: fused RMSNorm * gn_w * g * sigmoid(g) -> y (bf16) ----
  #pragma unroll
  for (int r = 0; r < 4; r++) {
    float ss = 0.f;
    #pragma unroll
    for (int vt = 0; vt < 16; vt++) ss += oacc[vt][r] * oacc[vt][r];
    #pragma unroll
    for (int off = 1; off < 16; off <<= 1) ss += __shfl_xor(ss, off);
    float rinv = rsqrtf(ss * (1.0f / 256.0f) + EPS);
    int tl = wvid * 16 + quad * 4 + r;
    const __bf16* grow = gg + (R + tl) * 1024 + F;
    __bf16* yrow = yout + (R + tl) * 1024 + F;
    #pragma unroll
    for (int vt = 0; vt < 16; vt++) {
      int v = vt * 16 + l16;
      float gvl = (float)grow[v];
      float yv = oacc[vt][r] * rinv * gns[v] * gvl / (1.0f + __expf(-gvl));
      yrow[v] = (__bf16)yv;
    }
  }
}

// ---------------------------------------------------------------------------
// Workspace layout (MB), peak 253 MB:
//   0-16 q | 16-32 k | 32-48 v -> AT | 48-64 g | 64-80 a | 80-96 xb -> VT
//   96-97 sgl/sgc/csA | 97-161 HKc | 161-225 HVc | 225-237 wt
//   237-253 KT -> y_bf
// ---------------------------------------------------------------------------
extern "C" void kernel_launch(void* const* d_in, const int* in_sizes, int n_in,
                              void* d_out, int out_size, void* d_ws, size_t ws_size,
                              hipStream_t stream) {
  using namespace abc;
  (void)in_sizes; (void)n_in; (void)out_size; (void)ws_size;
  const float* x    = (const float*)d_in[0];
  const float* q_w  = (const float*)d_in[1];
  const float* k_w  = (const float*)d_in[2];
  const float* v_w  = (const float*)d_in[3];
  const float* g_w  = (const float*)d_in[4];
  const float* s_w  = (const float*)d_in[5];
  const float* sg_w = (const float*)d_in[6];
  const float* gn_w = (const float*)d_in[7];
  const float* o_w  = (const float*)d_in[8];
  float* out = (float*)d_out;

  char* ws = (char*)d_ws;
  const size_t PROJ = (size_t)BT * 1024;       // elements per projection
  __bf16* proj = (__bf16*)ws;
  __bf16* q_bf = proj + 0 * PROJ;
  __bf16* k_bf = proj + 1 * PROJ;
  __bf16* v_bf = proj + 2 * PROJ;              // -> AT after transpose1
  __bf16* g_bf = proj + 3 * PROJ;
  __bf16* a_bf = proj + 4 * PROJ;
  __bf16* xb   = proj + 5 * PROJ;              // -> VT after proj gemm
  float* sgl = (float*)(ws + (size_t)96 * 1024 * 1024);
  float* sgc = sgl + (size_t)BH * T;
  float* csA = sgc + (size_t)BH * T;           // 16*32*256 floats
  __bf16* HKc = (__bf16*)(ws + (size_t)97 * 1024 * 1024);   // 64MB
  __bf16* HVc = HKc + (size_t)BH * NC * 65536;               // 64MB
  __bf16* wt  = (__bf16*)(ws + (size_t)225 * 1024 * 1024);  // 12MB
  __bf16* KT  = (__bf16*)(ws + (size_t)237 * 1024 * 1024);  // 16MB
  __bf16* VT  = xb;                            // overlay (xb dead)
  __bf16* AT  = v_bf;                          // overlay (v dead)
  __bf16* y_bf = KT;                           // overlay (KT dead)

  dim3 blk(256);
  dim3 blk512(512);
  cvt_w_kernel<<<dim3(16, 16, 6), blk, 0, stream>>>(q_w, k_w, v_w, g_w, s_w, o_w, wt);
  cvt_x_kernel<<<dim3(BT * 1024 / (256 * 8)), blk, 0, stream>>>(x, xb);
  gemm256_kernel<true, 5><<<dim3(32 * 4 * 5), blk512, 0, stream>>>(xb, wt, proj);
  sg_kernel<<<dim3(BT / 4), blk, 0, stream>>>(x, sg_w, sgl);
  scan_kernel<<<dim3(BH), blk, 0, stream>>>(sgl, sgc);
  prep_kernel<<<dim3(BT), blk, 0, stream>>>(q_bf, k_bf, a_bf, sgc);
  transpose_kernel<false, true><<<dim3(NC, BH, 2), blk, 0, stream>>>(k_bf, v_bf, KT, VT);
  transpose_kernel<true, true><<<dim3(NC, BH, 1), blk, 0, stream>>>(a_bf, a_bf, AT, AT);
  chunkstate_kernel<<<dim3(NC, BH, 4), blk, 0, stream>>>(KT, VT, AT, HKc, HVc, csA);
  prefix_state_kernel<<<dim3(32, BH, 2), blk, 0, stream>>>(HKc, HVc);
  prefix_csa_kernel<<<dim3(BH), blk, 0, stream>>>(csA);
  attn_kernel<<<dim3(NC, BH), blk, 0, stream>>>(
      q_bf, k_bf, a_bf, g_bf, AT, VT, HKc, HVc, csA, gn_w, y_bf);
  gemm256_kernel<false, 1><<<dim3(32 * 4), blk512, 0, stream>>>(
      y_bf, wt + (size_t)5 * 1024 * 1024, out);
}

// Round 5
// 468.196 us; speedup vs baseline: 1.1020x; 1.0121x over previous
//
#include <hip/hip_runtime.h>
#include <hip/hip_bf16.h>
#include <stdint.h>
#include <stddef.h>
#include <math.h>

typedef __bf16 bf8_t __attribute__((ext_vector_type(8)));
typedef float  f4_t  __attribute__((ext_vector_type(4)));
typedef unsigned int u32;

#define DEV static __device__ __forceinline__

namespace abc {
constexpr int B = 4, T = 2048, D = 1024, H = 4;
constexpr int BT = B * T;          // 8192
constexpr int CH = 64;             // chunk length
constexpr int NC = T / CH;         // 32 chunks
constexpr int BH = B * H;          // 16
constexpr float SCALE = 0.0625f;   // DK^-0.5
constexpr float GN = 16.0f;
constexpr float EPS = 1e-5f;
}

DEV f4_t mfma16(bf8_t a, bf8_t b, f4_t c) {
  return __builtin_amdgcn_mfma_f32_16x16x32_bf16(a, b, c, 0, 0, 0);
}

// async global->LDS, 16B per lane; lds dest must be wave-uniform base (+lane*16)
DEV void glds16(const void* g, void* l) {
  __builtin_amdgcn_global_load_lds(
      (const __attribute__((address_space(1))) u32*)g,
      (__attribute__((address_space(3))) u32*)l, 16, 0, 0);
}

// ---------------------------------------------------------------------------
// Slice-major pre-swizzled layout for attn MFMA B-operand matrices.
// slice = (colchunk cg32 = col/32) x (rowhalf rh = row/128), 4096 elems each:
// group p' = ((row&127)<<2) | (((col>>3)&3) ^ (row&3)).
// A wave's 64 bf8 fragment reads of one slice form ONE contiguous 1KB region.
// ---------------------------------------------------------------------------
DEV __bf16* slice_addr(__bf16* base, int row, int cg /*col/8*/) {
  return base + (((cg >> 2) * 2 + (row >> 7)) * 4096
               + ((((row & 127) << 2) | ((cg & 3) ^ (row & 3))) * 8));
}
DEV const __bf16* slice_addr(const __bf16* base, int row, int cg) {
  return base + (((cg >> 2) * 2 + (row >> 7)) * 4096
               + ((((row & 127) << 2) | ((cg & 3) ^ (row & 3))) * 8));
}

// ---------------------------------------------------------------------------
// GEMM slice-major pre-swizzled layout (row-half-major slice order):
// slice id = (row/128)*32 + (col/32); within slice (8KB):
// group p = ((row&127)<<2) | (((col>>3)&3) ^ ((row>>1)&3)), elem p*8+(col&7).
// Staging a slice = ONE contiguous 8KB read (1KB/wave bursts); the LDS image
// matches bfrag_g exactly (2-way-max bank conflicts on ds_read_b128).
// ---------------------------------------------------------------------------
DEV __bf16* gslice_addr(__bf16* base, int row, int col) {
  return base + ((size_t)((row >> 7) * 32 + (col >> 5)) * 4096
       + ((((row & 127) << 2) | (((col >> 3) & 3) ^ ((row >> 1) & 3))) * 8)
       + (col & 7));
}
DEV const __bf16* gslice_addr(const __bf16* base, int row, int col) {
  return base + ((size_t)((row >> 7) * 32 + (col >> 5)) * 4096
       + ((((row & 127) << 2) | (((col >> 3) & 3) ^ ((row >> 1) & 3))) * 8)
       + (col & 7));
}
DEV bf8_t bfrag_g(const __bf16* sl, int m, int quad) {
  return *reinterpret_cast<const bf8_t*>(sl + m * 32 + (((quad ^ (m >> 1)) & 3) << 3));
}

// ---------------------------------------------------------------------------
// x fp32 -> bf16 in GEMM slice-major layout. 8 elems (one 16B group)/thread.
// ---------------------------------------------------------------------------
__global__ __launch_bounds__(256)
void cvt_x_kernel(const float* __restrict__ x, __bf16* __restrict__ xs)
{
  const int idx = blockIdx.x * 256 + threadIdx.x;   // 1M groups total
  const int row = idx >> 7, c8 = idx & 127;
  const float4* src = reinterpret_cast<const float4*>(x);
  float4 a = src[(size_t)idx * 2];
  float4 b = src[(size_t)idx * 2 + 1];
  bf8_t o;
  o[0] = (__bf16)a.x; o[1] = (__bf16)a.y; o[2] = (__bf16)a.z; o[3] = (__bf16)a.w;
  o[4] = (__bf16)b.x; o[5] = (__bf16)b.y; o[6] = (__bf16)b.z; o[7] = (__bf16)b.w;
  *reinterpret_cast<bf8_t*>(gslice_addr(xs, row, c8 * 8)) = o;
}

// ---------------------------------------------------------------------------
// weight fp32 [k][n] -> bf16 [n][k] transposed into GEMM slice-major layout,
// 64x64 tiles, 6 weights
// ---------------------------------------------------------------------------
__global__ __launch_bounds__(256)
void cvt_w_kernel(const float* __restrict__ w0, const float* __restrict__ w1,
                  const float* __restrict__ w2, const float* __restrict__ w3,
                  const float* __restrict__ w4, const float* __restrict__ w5,
                  __bf16* __restrict__ wt)
{
  const int z = blockIdx.z;
  const float* W = (z == 0) ? w0 : (z == 1) ? w1 : (z == 2) ? w2
                 : (z == 3) ? w3 : (z == 4) ? w4 : w5;
  const int n0 = blockIdx.x * 64, k0 = blockIdx.y * 64;
  __shared__ __bf16 Ts[64][72];
  const int tid = threadIdx.x;
  #pragma unroll
  for (int i = 0; i < 4; i++) {
    int p = tid + 256 * i;            // 1024 float4 chunks: 64 k-rows x 16
    int row = p >> 4, c4 = p & 15;
    float4 v = *reinterpret_cast<const float4*>(W + (size_t)(k0 + row) * 1024 + n0 + c4 * 4);
    Ts[c4 * 4 + 0][row] = (__bf16)v.x;
    Ts[c4 * 4 + 1][row] = (__bf16)v.y;
    Ts[c4 * 4 + 2][row] = (__bf16)v.z;
    Ts[c4 * 4 + 3][row] = (__bf16)v.w;
  }
  __syncthreads();
  #pragma unroll
  for (int i = 0; i < 2; i++) {
    int p = tid + 256 * i;            // 512 bf8 chunks: 64 n-rows x 8
    int n = p >> 3, kq = p & 7;
    bf8_t o = *reinterpret_cast<const bf8_t*>(&Ts[n][kq * 8]);
    *reinterpret_cast<bf8_t*>(
        gslice_addr(wt + (size_t)z * 1024 * 1024, n0 + n, k0 + kq * 8)) = o;
  }
}

// ---------------------------------------------------------------------------
// 256x256-tile deep-pipelined GEMM (T2+T3+T4+T5):
//   C[8192 x 1024*NZ] = A[8192 x 1024] * Bt[z][n][k]^T
// A and Bt are in GEMM slice-major layout -> each staged slice is ONE
// contiguous 8KB read (1 glds16/thread, 1KB/wave bursts) instead of 16
// scattered 64B row-gathers.
// 512 threads = 8 waves (2M x 4N); per-wave output 128x64; BK=64.
// LDS 128KB: A/B double-buffered as 8KB swizzled slices.
// Per K-tile: 2 sub-phases {vmcnt(4)+barrier; 12 ds_read_b128; issue 4
// glds16 for tile t+1 into buf^1; setprio(1); 32 MFMA; setprio(0)}.
// vmcnt never drains to 0 mid-loop.
// ---------------------------------------------------------------------------
template<bool OUT_BF16, int NZ>
__global__ __launch_bounds__(512, 2)
void gemm256_kernel(const __bf16* __restrict__ A, const __bf16* __restrict__ BtB,
                    void* __restrict__ Cp)
{
  using namespace abc;
  constexpr int K = 1024;
  constexpr int NZT = 4 * NZ;              // (n,z) combos per m-tile
  const int bflat = blockIdx.x;            // 32*4*NZ blocks (mult of 8)
  const int xcd = bflat & 7;
  const int j = bflat >> 3;
  const int m_local = j / NZT;             // 0..3
  const int nz = j % NZT;
  const int nt = nz & 3, z = nz >> 2;
  const int m0 = (xcd * 4 + m_local) * 256;
  const int n0 = nt * 256;
  const __bf16* Bt = BtB + (size_t)z * K * 1024;

  __shared__ __bf16 LA[2][4][4096];   // [dbuf][half*2+ksub][slice] (64KB)
  __shared__ __bf16 LB[2][4][4096];   // (64KB)

  const int tid = threadIdx.x;
  const int lane = tid & 63, wv = tid >> 6;
  const int wr = wv >> 2, wc = wv & 3;     // wave row 0..1, wave col 0..3
  const int quad = lane >> 4, l16 = lane & 15;
  const f4_t fzero = {0.f, 0.f, 0.f, 0.f};
  f4_t acc[8][4];
  #pragma unroll
  for (int fr = 0; fr < 8; fr++)
    #pragma unroll
    for (int fc = 0; fc < 4; fc++) acc[fr][fc] = fzero;

  // stage the 4 slices (A-half0, A-half1, B-half0, B-half1) of (kt, ks):
  // contiguous 8KB each, 1 glds16/thread per slice.
  auto issue4 = [&](int kt, int ks) {
    const int db = kt & 1;
    const int kc = kt * 2 + ks;            // k-chunk of 32 (0..31)
    const __bf16* a0 = A  + (size_t)(((m0 >> 7) + 0) * 32 + kc) * 4096;
    const __bf16* a1 = A  + (size_t)(((m0 >> 7) + 1) * 32 + kc) * 4096;
    const __bf16* b0 = Bt + (size_t)(((n0 >> 7) + 0) * 32 + kc) * 4096;
    const __bf16* b1 = Bt + (size_t)(((n0 >> 7) + 1) * 32 + kc) * 4096;
    const int ldst = (tid & ~63) * 8;
    glds16(a0 + (size_t)tid * 8, &LA[db][0 + ks][ldst]);
    glds16(a1 + (size_t)tid * 8, &LA[db][2 + ks][ldst]);
    glds16(b0 + (size_t)tid * 8, &LB[db][0 + ks][ldst]);
    glds16(b1 + (size_t)tid * 8, &LB[db][2 + ks][ldst]);
  };

  issue4(0, 0); issue4(0, 1);

  for (int kt = 0; kt < 16; kt++) {
    const int db = kt & 1;
    const bool last = (kt == 15);
    #pragma unroll
    for (int ks = 0; ks < 2; ks++) {
      if (last && ks == 1) asm volatile("s_waitcnt vmcnt(0)\ns_barrier" ::: "memory");
      else                 asm volatile("s_waitcnt vmcnt(4)\ns_barrier" ::: "memory");
      bf8_t af[8], bfv[4];
      #pragma unroll
      for (int fr = 0; fr < 8; fr++)
        af[fr] = bfrag_g(&LA[db][wr * 2 + ks][0], fr * 16 + l16, quad);
      #pragma unroll
      for (int fc = 0; fc < 4; fc++)
        bfv[fc] = bfrag_g(&LB[db][(wc >> 1) * 2 + ks][0], (wc & 1) * 64 + fc * 16 + l16, quad);
      if (!last) issue4(kt + 1, ks);
      __builtin_amdgcn_s_setprio(1);
      #pragma unroll
      for (int fr = 0; fr < 8; fr++)
        #pragma unroll
        for (int fc = 0; fc < 4; fc++)
          acc[fr][fc] = mfma16(af[fr], bfv[fc], acc[fr][fc]);
      __builtin_amdgcn_s_setprio(0);
    }
  }

  const int crow = m0 + wr * 128, ccol = n0 + wc * 64;
  if (OUT_BF16) {
    __bf16* C = (__bf16*)Cp + (size_t)z * BT * 1024;
    #pragma unroll
    for (int fr = 0; fr < 8; fr++)
      #pragma unroll
      for (int fc = 0; fc < 4; fc++)
        #pragma unroll
        for (int r = 0; r < 4; r++)
          C[(size_t)(crow + fr * 16 + quad * 4 + r) * 1024 + ccol + fc * 16 + l16] =
              (__bf16)acc[fr][fc][r];
  } else {
    float* C = (float*)Cp;
    #pragma unroll
    for (int fr = 0; fr < 8; fr++)
      #pragma unroll
      for (int fc = 0; fc < 4; fc++)
        #pragma unroll
        for (int r = 0; r < 4; r++)
          C[(size_t)(crow + fr * 16 + quad * 4 + r) * 1024 + ccol + fc * 16 + l16] =
              acc[fr][fc][r];
  }
}

// ---------------------------------------------------------------------------
// sg projection
// ---------------------------------------------------------------------------
__global__ __launch_bounds__(256)
void sg_kernel(const float* __restrict__ x, const float* __restrict__ sgw,
               float* __restrict__ sgl)
{
  using namespace abc;
  const int wvid = threadIdx.x >> 6, lane = threadIdx.x & 63;
  const int bt = blockIdx.x * 4 + wvid;
  const float* xr = x + (size_t)bt * 1024;
  float a0 = 0, a1 = 0, a2 = 0, a3 = 0;
  #pragma unroll 4
  for (int u = 0; u < 16; u++) {
    int i = u * 64 + lane;
    float xv = xr[i];
    float4 w = *reinterpret_cast<const float4*>(sgw + (size_t)i * 4);
    a0 += xv * w.x; a1 += xv * w.y; a2 += xv * w.z; a3 += xv * w.w;
  }
  #pragma unroll
  for (int off = 32; off > 0; off >>= 1) {
    a0 += __shfl_down(a0, off);
    a1 += __shfl_down(a1, off);
    a2 += __shfl_down(a2, off);
    a3 += __shfl_down(a3, off);
  }
  if (lane == 0) {
    const int b = bt >> 11, t = bt & (T - 1);
    float r[4] = {a0, a1, a2, a3};
    #pragma unroll
    for (int h = 0; h < 4; h++) {
      float v = r[h];
      float ls = fminf(v, 0.f) - log1pf(expf(-fabsf(v)));
      sgl[(size_t)(b * 4 + h) * T + t] = ls * (1.0f / GN);
    }
  }
}

// ---------------------------------------------------------------------------
// inclusive cumsum over T per (b,h)
// ---------------------------------------------------------------------------
__global__ __launch_bounds__(256)
void scan_kernel(const float* __restrict__ sgl, float* __restrict__ sgc)
{
  using namespace abc;
  const int bh = blockIdx.x;
  const float* in = sgl + (size_t)bh * T;
  float* out = sgc + (size_t)bh * T;
  __shared__ float part[256];
  const int tid = threadIdx.x;
  float v[8]; float s = 0.f;
  #pragma unroll
  for (int i = 0; i < 8; i++) { v[i] = in[tid * 8 + i]; s += v[i]; }
  part[tid] = s;
  __syncthreads();
  for (int off = 1; off < 256; off <<= 1) {
    float a = (tid >= off) ? part[tid - off] : 0.f;
    __syncthreads();
    part[tid] += a;
    __syncthreads();
  }
  float run = (tid > 0) ? part[tid - 1] : 0.f;
  #pragma unroll
  for (int i = 0; i < 8; i++) { run += v[i]; out[tid * 8 + i] = run; }
}

// ---------------------------------------------------------------------------
// prep: RoPE(q), RoPE(k)*exp(cumsum sg), s -> exp(clamp(s)) ; in-place on bf16
// ---------------------------------------------------------------------------
__global__ __launch_bounds__(256)
void prep_kernel(__bf16* __restrict__ q, __bf16* __restrict__ k,
                 __bf16* __restrict__ s, const float* __restrict__ sgc)
{
  using namespace abc;
  const int bt = blockIdx.x;
  const int b = bt >> 11, t = bt & (T - 1);
  const int tid = threadIdx.x;
  const size_t ro = (size_t)bt * 1024;
  #pragma unroll
  for (int i = 0; i < 2; i++) {
    int p = tid + 256 * i;          // 0..511 : h = p/128, d = p%128
    int h = p >> 7, d = p & 127;
    float inv = expf(-(float)d * (9.210340371976184f / 128.0f)); // 10000^(-d/128)
    float ang = (float)t * inv;
    float sn, cs;
    sincosf(ang, &sn, &cs);
    size_t base = ro + (size_t)h * 256 + d;
    float q1 = (float)q[base], q2 = (float)q[base + 128];
    q[base]       = (__bf16)(q1 * cs - q2 * sn);
    q[base + 128] = (__bf16)(q2 * cs + q1 * sn);
    float dec = expf(sgc[(size_t)(b * 4 + h) * T + t]);
    float k1 = (float)k[base], k2 = (float)k[base + 128];
    k[base]       = (__bf16)((k1 * cs - k2 * sn) * dec);
    k[base + 128] = (__bf16)((k2 * cs + k1 * sn) * dec);
  }
  #pragma unroll
  for (int i = 0; i < 4; i++) {
    int e = tid + 256 * i;
    float v = (float)s[ro + e];
    v = fminf(fmaxf(v, -32.f), 32.f);
    s[ro + e] = (__bf16)expf(v);
  }
}

// ---------------------------------------------------------------------------
// transpose chunks: [t=64][f=256] -> per-chunk [f=256][t=64]; dest layout is
// either row-major (KT, for chunkstate) or slice-major pre-swizzled (VT/AT).
// ---------------------------------------------------------------------------
template<bool NEW0, bool NEW1>
__global__ __launch_bounds__(256)
void transpose_kernel(const __bf16* __restrict__ s0, const __bf16* __restrict__ s1,
                      __bf16* __restrict__ d0, __bf16* __restrict__ d1)
{
  using namespace abc;
  const int c = blockIdx.x, bh = blockIdx.y, z = blockIdx.z;
  const int b = bh >> 2, h = bh & 3;
  const size_t R = (size_t)b * T + (size_t)c * CH;
  const int F = h * 256;
  const __bf16* src = z ? s1 : s0;
  __bf16* dst = (z ? d1 : d0) + ((size_t)bh * NC + c) * (256 * 64);
  const bool NEWL = z ? NEW1 : NEW0;
  __shared__ __bf16 L[256 * 64];
  const int tid = threadIdx.x;
  #pragma unroll
  for (int j = 0; j < 8; j++) {
    int p = tid + 256 * j;            // (t = p>>5, fc = p&31)
    int t = p >> 5, fc = p & 31;
    bf8_t v = *reinterpret_cast<const bf8_t*>(src + (R + t) * 1024 + F + fc * 8);
    const int sw = ((t >> 3) ^ (fc & 7)) * 8 + (t & 7);
    #pragma unroll
    for (int u = 0; u < 8; u++)
      L[(fc * 8 + u) * 64 + sw] = v[u];
  }
  __syncthreads();
  #pragma unroll
  for (int j = 0; j < 8; j++) {
    int p = tid + 256 * j;            // (f = p>>3, q = p&7)
    int f = p >> 3, q = p & 7;
    int phys = q ^ ((f >> 3) & 7);
    bf8_t o = *reinterpret_cast<const bf8_t*>(&L[f * 64 + phys * 8]);
    __bf16* daddr = NEWL ? slice_addr(dst, f, q)
                         : dst + (size_t)f * 64 + q * 8;
    *reinterpret_cast<bf8_t*>(daddr) = o;
  }
}

// ---------------------------------------------------------------------------
// per-chunk states. KT is row-major [f][t]; VT/AT are slice-major swizzled.
// HKc/HVc outputs are written slice-major swizzled.
// ---------------------------------------------------------------------------
__global__ __launch_bounds__(256)
void chunkstate_kernel(const __bf16* __restrict__ KT, const __bf16* __restrict__ VT,
                       const __bf16* __restrict__ AT,
                       __bf16* __restrict__ HKc, __bf16* __restrict__ HVc,
                       float* __restrict__ csA)
{
  using namespace abc;
  const int c = blockIdx.x, bh = blockIdx.y, part = blockIdx.z;
  const size_t TB = ((size_t)bh * NC + c) * (256 * 64);
  const bool isHV = part >= 2;
  const int p2 = part & 1;
  const __bf16* Aop = (isHV ? VT : AT) + TB;   // rows = out-dim (v or m); slice-major
  const __bf16* Bop = (isHV ? AT : KT) + TB;   // rows = out-col (m: slice-major | k: row-major)
  const int tid = threadIdx.x;
  if (part == 2) {
    float ssum = 0.f;
    #pragma unroll
    for (int u = 0; u < 8; u++) {
      bf8_t v = *reinterpret_cast<const bf8_t*>(slice_addr(AT + TB, tid, u));
      #pragma unroll
      for (int w = 0; w < 8; w++) ssum += (float)v[w];
    }
    csA[((size_t)bh * NC + c) * 256 + tid] = ssum;
  }
  const int lane = tid & 63, wvid = tid >> 6;
  const int quad = lane >> 4, l16 = lane & 15;
  const int row0 = p2 * 128 + wvid * 32;
  const f4_t fzero = {0.f, 0.f, 0.f, 0.f};
  f4_t acc[2][16];
  #pragma unroll
  for (int a = 0; a < 2; a++)
    #pragma unroll
    for (int ct = 0; ct < 16; ct++) acc[a][ct] = fzero;
  #pragma unroll
  for (int ks = 0; ks < 2; ks++) {
    const int cg = ks * 4 + quad;
    bf8_t af0 = *reinterpret_cast<const bf8_t*>(slice_addr(Aop, row0 + l16, cg));
    bf8_t af1 = *reinterpret_cast<const bf8_t*>(slice_addr(Aop, row0 + 16 + l16, cg));
    #pragma unroll
    for (int ct = 0; ct < 16; ct++) {
      bf8_t bv;
      if (isHV)
        bv = *reinterpret_cast<const bf8_t*>(slice_addr(Bop, ct * 16 + l16, cg));
      else
        bv = *reinterpret_cast<const bf8_t*>(Bop + (size_t)(ct * 16 + l16) * 64 + ks * 32 + quad * 8);
      acc[0][ct] = mfma16(af0, bv, acc[0][ct]);
      acc[1][ct] = mfma16(af1, bv, acc[1][ct]);
    }
  }
  __bf16* out = (isHV ? HVc : HKc) + ((size_t)bh * NC + c) * 65536;
  #pragma unroll
  for (int rt = 0; rt < 2; rt++)
    #pragma unroll
    for (int ct = 0; ct < 16; ct++)
      #pragma unroll
      for (int r = 0; r < 4; r++) {
        const int mg = row0 + rt * 16 + quad * 4 + r;   // out row 0..255
        const int n  = ct * 16 + l16;                    // out col 0..255
        *(slice_addr(out, mg, n >> 3) + (n & 7)) = (__bf16)acc[rt][ct][r];
      }
}

// ---------------------------------------------------------------------------
// in-place exclusive prefix over chunk axis of HKc/HVc (bf16, fp32 run)
// ---------------------------------------------------------------------------
__global__ __launch_bounds__(256)
void prefix_state_kernel(__bf16* __restrict__ HKc, __bf16* __restrict__ HVc)
{
  using namespace abc;
  const int bh = blockIdx.y;
  __bf16* base = (blockIdx.z ? HVc : HKc) + (size_t)bh * NC * 65536;
  const int e = (blockIdx.x * 256 + threadIdx.x) * 8;
  float run[8];
  #pragma unroll
  for (int u = 0; u < 8; u++) run[u] = 0.f;
  #pragma unroll 4
  for (int c = 0; c < NC; c++) {
    __bf16* p = base + (size_t)c * 65536 + e;
    bf8_t v = *reinterpret_cast<const bf8_t*>(p);
    bf8_t o;
    #pragma unroll
    for (int u = 0; u < 8; u++) { o[u] = (__bf16)run[u]; run[u] += (float)v[u]; }
    *reinterpret_cast<bf8_t*>(p) = o;
  }
}

__global__ __launch_bounds__(256)
void prefix_csa_kernel(float* __restrict__ csA)
{
  using namespace abc;
  const int bh = blockIdx.x, m = threadIdx.x;
  float run = 0.f;
  for (int c = 0; c < NC; c++) {
    float* p = csA + ((size_t)bh * NC + c) * 256 + m;
    float v = *p; *p = run; run += v;
  }
}

// ---------------------------------------------------------------------------
// main chunked ABC attention + fused RMSNorm/SiLU-gate epilogue.
// NO LDS STAGING: every MFMA B-fragment is loaded straight from global into
// VGPRs (slice-major operands -> a wave's 64 fragment loads form ONE
// contiguous 1KB burst; row-major K/A -> 16x64B). Waves fully independent.
// y output is written in GEMM slice-major layout (feeds output GEMM's A).
// ---------------------------------------------------------------------------
__global__ __launch_bounds__(256)
void attn_kernel(const __bf16* __restrict__ qg, const __bf16* __restrict__ kg,
                 const __bf16* __restrict__ ag, const __bf16* __restrict__ gg,
                 const __bf16* __restrict__ ATp, const __bf16* __restrict__ VTp,
                 const __bf16* __restrict__ HKp, const __bf16* __restrict__ HVp,
                 const float* __restrict__ Zp, const float* __restrict__ gnw,
                 __bf16* __restrict__ yout)
{
  using namespace abc;
  const int c = blockIdx.x, bh = blockIdx.y;
  const int b = bh >> 2, h = bh & 3;
  const size_t R = (size_t)b * T + (size_t)c * CH;
  const int F = h * 256;
  const int tid = threadIdx.x;
  const int lane = tid & 63, wvid = tid >> 6;
  const int quad = lane >> 4, l16 = lane & 15;

  __shared__ __bf16 Ws[64][264];   // W = qv / SumA (per-wave strip)
  __shared__ __bf16 S1s[64][72];   // masked QK^T, later masked P (per-wave strip)
  __shared__ float zs[256];
  __shared__ float gns[256];

  const __bf16* atb = ATp + ((size_t)bh * NC + c) * (256 * 64);
  const __bf16* vtb = VTp + ((size_t)bh * NC + c) * (256 * 64);
  const __bf16* hkb = HKp + ((size_t)bh * NC + c) * 65536;
  const __bf16* hvb = HVp + ((size_t)bh * NC + c) * 65536;
  const __bf16* kbase = kg + R * 1024 + F;
  const __bf16* abase = ag + R * 1024 + F;

  zs[tid] = Zp[((size_t)bh * NC + c) * 256 + tid];
  gns[tid] = gnw[tid];
  __syncthreads();   // publish zs/gns (the only block-wide sync)

  // per-lane element offset inside an 8KB slice for fragment reads:
  // row = m8*16 + l16, colgroup = quad  ->  m8*512 + lsw
  const int lsw = l16 * 32 + ((quad ^ (l16 & 3)) << 3);
  const int rowoff = l16 * 1024 + quad * 8;   // row-major K/A fragment base

  // preload Q fragments (row = own strip row, all 8 k-groups)
  const __bf16* qrow = qg + (R + wvid * 16 + l16) * 1024 + F;
  bf8_t aq[8];
  #pragma unroll
  for (int ks = 0; ks < 8; ks++)
    aq[ks] = *reinterpret_cast<const bf8_t*>(qrow + ks * 32 + quad * 8);

  const f4_t fzero = {0.f, 0.f, 0.f, 0.f};

  // ---- phase A: S1 = Q K^T ----
  f4_t s1a[4];
  #pragma unroll
  for (int it = 0; it < 4; it++) s1a[it] = fzero;
  #pragma unroll
  for (int ks = 0; ks < 8; ks++) {
    #pragma unroll
    for (int it = 0; it < 4; it++) {
      bf8_t bk = *reinterpret_cast<const bf8_t*>(kbase + it * 16 * 1024 + rowoff + ks * 32);
      s1a[it] = mfma16(aq[ks], bk, s1a[it]);
    }
  }
  #pragma unroll
  for (int it = 0; it < 4; it++)
    #pragma unroll
    for (int r = 0; r < 4; r++) {
      int tl = wvid * 16 + quad * 4 + r;
      int il = it * 16 + l16;
      S1s[tl][il] = (il <= tl) ? (__bf16)s1a[it][r] : (__bf16)0.0f;
    }

  // ---- phase B: intra numerator + cumA (AT, slice-major) ----
  f4_t aok[16], acum[16];
  #pragma unroll
  for (int mt = 0; mt < 16; mt++) { aok[mt] = fzero; acum[mt] = fzero; }
  #pragma unroll
  for (int iks = 0; iks < 2; iks++) {
    bf8_t s1f = *reinterpret_cast<const bf8_t*>(&S1s[wvid * 16 + l16][iks * 32 + quad * 8]);
    bf8_t lf;
    #pragma unroll
    for (int u = 0; u < 8; u++)
      lf[u] = (iks * 32 + quad * 8 + u <= wvid * 16 + l16) ? (__bf16)1.0f : (__bf16)0.0f;
    #pragma unroll
    for (int rh = 0; rh < 2; rh++) {
      #pragma unroll
      for (int m8 = 0; m8 < 8; m8++) {
        bf8_t bfa = *reinterpret_cast<const bf8_t*>(atb + (iks * 2 + rh) * 4096 + m8 * 512 + lsw);
        aok[rh * 8 + m8]  = mfma16(s1f, bfa, aok[rh * 8 + m8]);
        acum[rh * 8 + m8] = mfma16(lf,  bfa, acum[rh * 8 + m8]);
      }
    }
  }

  // ---- phase C: cross numerator Q @ HKpre (slice-major) ----
  #pragma unroll
  for (int ks = 0; ks < 8; ks++) {
    #pragma unroll
    for (int rh = 0; rh < 2; rh++) {
      #pragma unroll
      for (int m8 = 0; m8 < 8; m8++) {
        bf8_t bv = *reinterpret_cast<const bf8_t*>(hkb + (ks * 2 + rh) * 4096 + m8 * 512 + lsw);
        aok[rh * 8 + m8] = mfma16(aq[ks], bv, aok[rh * 8 + m8]);
      }
    }
  }

  // ---- softmax over m ; W = qv / SumA (wave-private strip) ----
  #pragma unroll
  for (int r = 0; r < 4; r++) {
    float ovv[16], sa[16];
    float mx = -3.0e38f;
    #pragma unroll
    for (int mt = 0; mt < 16; mt++) {
      sa[mt] = zs[mt * 16 + l16] + acum[mt][r];
      ovv[mt] = SCALE * aok[mt][r] / sa[mt];
      mx = fmaxf(mx, ovv[mt]);
    }
    #pragma unroll
    for (int off = 1; off < 16; off <<= 1) mx = fmaxf(mx, __shfl_xor(mx, off));
    float se = 0.f;
    #pragma unroll
    for (int mt = 0; mt < 16; mt++) { ovv[mt] = __expf(ovv[mt] - mx); se += ovv[mt]; }
    #pragma unroll
    for (int off = 1; off < 16; off <<= 1) se += __shfl_xor(se, off);
    float inv = 1.0f / se;
    int tl = wvid * 16 + quad * 4 + r;
    #pragma unroll
    for (int mt = 0; mt < 16; mt++)
      Ws[tl][mt * 16 + l16] = (__bf16)(ovv[mt] * inv / sa[mt]);
  }

  // ---- phase 4a: P = mask(W @ A^T) (row-major A) ----
  f4_t pacc[4];
  #pragma unroll
  for (int it = 0; it < 4; it++) pacc[it] = fzero;
  #pragma unroll
  for (int ks = 0; ks < 8; ks++) {
    bf8_t wf = *reinterpret_cast<const bf8_t*>(&Ws[wvid * 16 + l16][ks * 32 + quad * 8]);
    #pragma unroll
    for (int it = 0; it < 4; it++) {
      bf8_t ba = *reinterpret_cast<const bf8_t*>(abase + it * 16 * 1024 + rowoff + ks * 32);
      pacc[it] = mfma16(wf, ba, pacc[it]);
    }
  }
  #pragma unroll
  for (int it = 0; it < 4; it++)
    #pragma unroll
    for (int r = 0; r < 4; r++) {
      int tl = wvid * 16 + quad * 4 + r;
      int il = it * 16 + l16;
      S1s[tl][il] = (il <= tl) ? (__bf16)pacc[it][r] : (__bf16)0.0f;
    }

  // ---- phase 4b-1: O = W @ HVpre^T (slice-major) ----
  f4_t oacc[16];
  #pragma unroll
  for (int vt = 0; vt < 16; vt++) oacc[vt] = fzero;
  #pragma unroll
  for (int ks = 0; ks < 8; ks++) {
    bf8_t wf = *reinterpret_cast<const bf8_t*>(&Ws[wvid * 16 + l16][ks * 32 + quad * 8]);
    #pragma unroll
    for (int rh = 0; rh < 2; rh++) {
      #pragma unroll
      for (int v8 = 0; v8 < 8; v8++) {
        bf8_t bv = *reinterpret_cast<const bf8_t*>(hvb + (ks * 2 + rh) * 4096 + v8 * 512 + lsw);
        oacc[rh * 8 + v8] = mfma16(wf, bv, oacc[rh * 8 + v8]);
      }
    }
  }

  // ---- phase 4b-2: O += P @ V (slice-major VT) ----
  #pragma unroll
  for (int iks = 0; iks < 2; iks++) {
    bf8_t pf = *reinterpret_cast<const bf8_t*>(&S1s[wvid * 16 + l16][iks * 32 + quad * 8]);
    #pragma unroll
    for (int rh = 0; rh < 2; rh++) {
      #pragma unroll
      for (int v8 = 0; v8 < 8; v8++) {
        bf8_t bvt = *reinterpret_cast<const bf8_t*>(vtb + (iks * 2 + rh) * 4096 + v8 * 512 + lsw);
        oacc[rh * 8 + v8] = mfma16(pf, bvt, oacc[rh * 8 + v8]);
      }
    }
  }

  // ---- epilogue: fused RMSNorm * gn_w * g * sigmoid(g) -> y (GEMM-slice) ----
  #pragma unroll
  for (int r = 0; r < 4; r++) {
    float ss = 0.f;
    #pragma unroll
    for (int vt = 0; vt < 16; vt++) ss += oacc[vt][r] * oacc[vt][r];
    #pragma unroll
    for (int off = 1; off < 16; off <<= 1) ss += __shfl_xor(ss, off);
    float rinv = rsqrtf(ss * (1.0f / 256.0f) + EPS);
    int tl = wvid * 16 + quad * 4 + r;
    const __bf16* grow = gg + (R + tl) * 1024 + F;
    #pragma unroll
    for (int vt = 0; vt < 16; vt++) {
      int v = vt * 16 + l16;
      float gvl = (float)grow[v];
      float yv = oacc[vt][r] * rinv * gns[v] * gvl / (1.0f + __expf(-gvl));
      *gslice_addr(yout, (int)(R + tl), F + v) = (__bf16)yv;
    }
  }
}

// ---------------------------------------------------------------------------
// Workspace layout (MB), peak 253 MB:
//   0-16 q | 16-32 k | 32-48 v -> AT | 48-64 g | 64-80 a | 80-96 xb -> VT
//   96-97 sgl/sgc/csA | 97-161 HKc | 161-225 HVc | 225-237 wt
//   237-253 KT -> y_bf
// ---------------------------------------------------------------------------
extern "C" void kernel_launch(void* const* d_in, const int* in_sizes, int n_in,
                              void* d_out, int out_size, void* d_ws, size_t ws_size,
                              hipStream_t stream) {
  using namespace abc;
  (void)in_sizes; (void)n_in; (void)out_size; (void)ws_size;
  const float* x    = (const float*)d_in[0];
  const float* q_w  = (const float*)d_in[1];
  const float* k_w  = (const float*)d_in[2];
  const float* v_w  = (const float*)d_in[3];
  const float* g_w  = (const float*)d_in[4];
  const float* s_w  = (const float*)d_in[5];
  const float* sg_w = (const float*)d_in[6];
  const float* gn_w = (const float*)d_in[7];
  const float* o_w  = (const float*)d_in[8];
  float* out = (float*)d_out;

  char* ws = (char*)d_ws;
  const size_t PROJ = (size_t)BT * 1024;       // elements per projection
  __bf16* proj = (__bf16*)ws;
  __bf16* q_bf = proj + 0 * PROJ;
  __bf16* k_bf = proj + 1 * PROJ;
  __bf16* v_bf = proj + 2 * PROJ;              // -> AT after transpose1
  __bf16* g_bf = proj + 3 * PROJ;
  __bf16* a_bf = proj + 4 * PROJ;
  __bf16* xb   = proj + 5 * PROJ;              // -> VT after proj gemm
  float* sgl = (float*)(ws + (size_t)96 * 1024 * 1024);
  float* sgc = sgl + (size_t)BH * T;
  float* csA = sgc + (size_t)BH * T;           // 16*32*256 floats
  __bf16* HKc = (__bf16*)(ws + (size_t)97 * 1024 * 1024);   // 64MB
  __bf16* HVc = HKc + (size_t)BH * NC * 65536;               // 64MB
  __bf16* wt  = (__bf16*)(ws + (size_t)225 * 1024 * 1024);  // 12MB
  __bf16* KT  = (__bf16*)(ws + (size_t)237 * 1024 * 1024);  // 16MB
  __bf16* VT  = xb;                            // overlay (xb dead)
  __bf16* AT  = v_bf;                          // overlay (v dead)
  __bf16* y_bf = KT;                           // overlay (KT dead)

  dim3 blk(256);
  dim3 blk512(512);
  cvt_w_kernel<<<dim3(16, 16, 6), blk, 0, stream>>>(q_w, k_w, v_w, g_w, s_w, o_w, wt);
  cvt_x_kernel<<<dim3(BT * 1024 / (256 * 8)), blk, 0, stream>>>(x, xb);
  gemm256_kernel<true, 5><<<dim3(32 * 4 * 5), blk512, 0, stream>>>(xb, wt, proj);
  sg_kernel<<<dim3(BT / 4), blk, 0, stream>>>(x, sg_w, sgl);
  scan_kernel<<<dim3(BH), blk, 0, stream>>>(sgl, sgc);
  prep_kernel<<<dim3(BT), blk, 0, stream>>>(q_bf, k_bf, a_bf, sgc);
  transpose_kernel<false, true><<<dim3(NC, BH, 2), blk, 0, stream>>>(k_bf, v_bf, KT, VT);
  transpose_kernel<true, true><<<dim3(NC, BH, 1), blk, 0, stream>>>(a_bf, a_bf, AT, AT);
  chunkstate_kernel<<<dim3(NC, BH, 4), blk, 0, stream>>>(KT, VT, AT, HKc, HVc, csA);
  prefix_state_kernel<<<dim3(32, BH, 2), blk, 0, stream>>>(HKc, HVc);
  prefix_csa_kernel<<<dim3(BH), blk, 0, stream>>>(csA);
  attn_kernel<<<dim3(NC, BH), blk, 0, stream>>>(
      q_bf, k_bf, a_bf, g_bf, AT, VT, HKc, HVc, csA, gn_w, y_bf);
  gemm256_kernel<false, 1><<<dim3(32 * 4), blk512, 0, stream>>>(
      y_bf, wt + (size_t)5 * 1024 * 1024, out);
}